// Round 7
// baseline (201.286 us; speedup 1.0000x reference)
//
#include <hip/hip_runtime.h>
#include <math.h>

// Problem constants (SemanticAwareTransitions_9826885173968)
#define V_  512
#define D_  256
#define H_  8
#define DH_ 32
#define FF_ 2048
#define L_  2
#define B_  4
#define S_  128
#define T_  (B_*S_)   // 512 tokens

typedef float f32x4 __attribute__((ext_vector_type(4)));
typedef short s16x8 __attribute__((ext_vector_type(8)));
typedef unsigned short u16x4 __attribute__((ext_vector_type(4)));
typedef unsigned short ushort_t;

// fp32 -> bf16 bits, round-to-nearest-even
__device__ __forceinline__ ushort_t f2b(float f) {
    unsigned int u = __builtin_bit_cast(unsigned int, f);
    u += 0x7FFFu + ((u >> 16) & 1u);
    return (ushort_t)(u >> 16);
}
__device__ __forceinline__ float b2f(ushort_t h) {
    unsigned int u = ((unsigned int)h) << 16;
    return __builtin_bit_cast(float, u);
}

__device__ __forceinline__ float waveReduceSum(float v) {
#pragma unroll
    for (int off = 32; off > 0; off >>= 1) v += __shfl_xor(v, off);
    return v;
}
__device__ __forceinline__ float waveReduceMax(float v) {
#pragma unroll
    for (int off = 32; off > 0; off >>= 1) v = fmaxf(v, __shfl_xor(v, off));
    return v;
}

// ---------------------------------------------------------------------------
// bf16 MFMA GEMM (64x64 tile, BK=64, 4 waves), double-buffered 1-barrier
// pipeline (lgkmcnt-only barrier; global loads stay in flight across it).
// Used for W1, W2 (split-K) and logits.
// mfma_f32_16x16x32_bf16 D-layout: col=lane&15, row=(lane>>4)*4+reg.
// ---------------------------------------------------------------------------
template<int RELU, int OUTB, int BIAS>
__device__ __forceinline__ void mgemm_body(
    const ushort_t* __restrict__ A, const ushort_t* __restrict__ BT,
    const float* __restrict__ bias, float* __restrict__ Cf,
    ushort_t* __restrict__ Cb, int M, int N, int K, int kBegin, int kSteps)
{
    __shared__ ushort_t Al[2][64][72];
    __shared__ ushort_t Bl[2][64][72];
    const int tid  = threadIdx.x;
    const int m0   = blockIdx.y * 64, n0 = blockIdx.x * 64;
    const int lane = tid & 63, w = tid >> 6;
    const int srow = tid >> 2, sseg = (tid & 3) * 16;
    const int l15  = lane & 15,  kg = (lane >> 4) * 8;

    f32x4 acc0 = {0.f,0.f,0.f,0.f}, acc1 = acc0, acc2 = acc0, acc3 = acc0;

    const ushort_t* Aptr = &A [(size_t)(m0 + srow) * K + kBegin + sseg];
    const ushort_t* Bptr = &BT[(size_t)(n0 + srow) * K + kBegin + sseg];

    s16x8 av0 = *(const s16x8*)Aptr,       av1 = *(const s16x8*)(Aptr + 8);
    s16x8 bv0 = *(const s16x8*)Bptr,       bv1 = *(const s16x8*)(Bptr + 8);
    *(s16x8*)&Al[0][srow][sseg]     = av0;
    *(s16x8*)&Al[0][srow][sseg + 8] = av1;
    *(s16x8*)&Bl[0][srow][sseg]     = bv0;
    *(s16x8*)&Bl[0][srow][sseg + 8] = bv1;

    for (int kt = 0; kt < kSteps; ++kt) {
        const int cur = kt & 1;
        const bool more = (kt + 1 < kSteps);
        if (more) {
            const size_t o = (size_t)(kt + 1) * 64;
            av0 = *(const s16x8*)(Aptr + o);     av1 = *(const s16x8*)(Aptr + o + 8);
            bv0 = *(const s16x8*)(Bptr + o);     bv1 = *(const s16x8*)(Bptr + o + 8);
        }
        asm volatile("s_waitcnt lgkmcnt(0)\n\ts_barrier" ::: "memory");

        s16x8 b0 = *(const s16x8*)&Bl[cur][w * 16 + l15][kg];
        s16x8 b1 = *(const s16x8*)&Bl[cur][w * 16 + l15][kg + 32];
        s16x8 a00 = *(const s16x8*)&Al[cur][     l15][kg];
        s16x8 a01 = *(const s16x8*)&Al[cur][     l15][kg + 32];
        s16x8 a10 = *(const s16x8*)&Al[cur][16 + l15][kg];
        s16x8 a11 = *(const s16x8*)&Al[cur][16 + l15][kg + 32];
        s16x8 a20 = *(const s16x8*)&Al[cur][32 + l15][kg];
        s16x8 a21 = *(const s16x8*)&Al[cur][32 + l15][kg + 32];
        s16x8 a30 = *(const s16x8*)&Al[cur][48 + l15][kg];
        s16x8 a31 = *(const s16x8*)&Al[cur][48 + l15][kg + 32];
        acc0 = __builtin_amdgcn_mfma_f32_16x16x32_bf16(a00, b0, acc0, 0, 0, 0);
        acc1 = __builtin_amdgcn_mfma_f32_16x16x32_bf16(a10, b0, acc1, 0, 0, 0);
        acc2 = __builtin_amdgcn_mfma_f32_16x16x32_bf16(a20, b0, acc2, 0, 0, 0);
        acc3 = __builtin_amdgcn_mfma_f32_16x16x32_bf16(a30, b0, acc3, 0, 0, 0);
        acc0 = __builtin_amdgcn_mfma_f32_16x16x32_bf16(a01, b1, acc0, 0, 0, 0);
        acc1 = __builtin_amdgcn_mfma_f32_16x16x32_bf16(a11, b1, acc1, 0, 0, 0);
        acc2 = __builtin_amdgcn_mfma_f32_16x16x32_bf16(a21, b1, acc2, 0, 0, 0);
        acc3 = __builtin_amdgcn_mfma_f32_16x16x32_bf16(a31, b1, acc3, 0, 0, 0);

        if (more) {
            *(s16x8*)&Al[cur ^ 1][srow][sseg]     = av0;
            *(s16x8*)&Al[cur ^ 1][srow][sseg + 8] = av1;
            *(s16x8*)&Bl[cur ^ 1][srow][sseg]     = bv0;
            *(s16x8*)&Bl[cur ^ 1][srow][sseg + 8] = bv1;
        }
    }

    const int col = n0 + w * 16 + l15;
    const float bb = BIAS ? bias[col] : 0.f;
    f32x4 accs[4] = {acc0, acc1, acc2, acc3};
#pragma unroll
    for (int r = 0; r < 4; ++r) {
#pragma unroll
        for (int e = 0; e < 4; ++e) {
            const int row = m0 + r * 16 + (lane >> 4) * 4 + e;
            float v = accs[r][e] + bb;
            if (RELU) v = fmaxf(v, 0.f);
            if (OUTB) Cb[(size_t)row * N + col] = f2b(v);
            else      Cf[(size_t)row * N + col] = v;
        }
    }
}

// Split-K: z<2 writes Cf0 + z*M*N ; z>=2 writes Cf1 + (z-2)*M*N (fp32).
template<int RELU, int OUTB, int BIAS>
__global__ __launch_bounds__(256) void mgemm_k(const ushort_t* A, const ushort_t* BT,
    const float* bias, float* Cf0, float* Cf1, ushort_t* Cb,
    int M, int N, int K, int kChunk)
{
    const int z = blockIdx.z;
    float* Cfz = nullptr;
    if (Cf0) Cfz = (z < 2) ? Cf0 + (size_t)z * M * N
                           : Cf1 + (size_t)(z - 2) * M * N;
    mgemm_body<RELU, OUTB, BIAS>(A, BT, bias, Cfz, Cb, M, N, K,
                                 z * kChunk, kChunk / 64);
}

// ---------------------------------------------------------------------------
// Fused QKV projection + attention. One block per (b,h), 512 thr = 8 waves.
// Projection: register-streaming MFMA (A/B frags direct from L2, no LDS, no
// barriers). Waves 0-3: Q rows w*32; waves 4-5: K rows (w-4)*64; 6-7: V.
// Output Q/K/V fp32 in LDS (55KB). Then VALU attention: thread = (row i,
// j-slice jg), P in registers, 4-lane shfl reduces.
// ---------------------------------------------------------------------------
__global__ __launch_bounds__(512) void qkvattn_k(
    const ushort_t* __restrict__ Xb, const ushort_t* __restrict__ WT,
    const float* __restrict__ bq, const float* __restrict__ bk,
    const float* __restrict__ bv, ushort_t* __restrict__ Ob)
{
    __shared__ float Qs[128][36], Ks[128][36], Vs[128][36];
    const int bh = blockIdx.x, b = bh >> 3, h = bh & 7;
    const int tid = threadIdx.x;
    const int w = tid >> 6, lane = tid & 63;
    const int l15 = lane & 15, kg = (lane >> 4) * 8;

    {   // ---- projection phase (no barriers until the end) ----
        const ushort_t* WB; const float* bias; float (*dst)[36];
        int rowbase, nrf;
        if (w < 4)      { WB = WT;               bias = bq; dst = Qs; rowbase = w * 32;       nrf = 2; }
        else if (w < 6) { WB = WT + D_ * D_;     bias = bk; dst = Ks; rowbase = (w - 4) * 64; nrf = 4; }
        else            { WB = WT + 2 * D_ * D_; bias = bv; dst = Vs; rowbase = (w - 6) * 64; nrf = 4; }

        f32x4 acc[4][2] = {};
        const ushort_t* Abase = Xb + (size_t)(b * S_ + rowbase) * D_;
        const ushort_t* Bbase = WB + (size_t)(h * DH_) * D_;
#pragma unroll
        for (int kk = 0; kk < 8; ++kk) {
            const int k0 = kk * 32 + kg;
            s16x8 bf0 = *(const s16x8*)&Bbase[(size_t)l15 * D_ + k0];
            s16x8 bf1 = *(const s16x8*)&Bbase[(size_t)(16 + l15) * D_ + k0];
#pragma unroll
            for (int rf = 0; rf < 4; ++rf) {
                if (rf < nrf) {
                    s16x8 af = *(const s16x8*)&Abase[(size_t)(rf * 16 + l15) * D_ + k0];
                    acc[rf][0] = __builtin_amdgcn_mfma_f32_16x16x32_bf16(af, bf0, acc[rf][0], 0, 0, 0);
                    acc[rf][1] = __builtin_amdgcn_mfma_f32_16x16x32_bf16(af, bf1, acc[rf][1], 0, 0, 0);
                }
            }
        }
        const int r0 = (lane >> 4) * 4;
#pragma unroll
        for (int rf = 0; rf < 4; ++rf) {
            if (rf < nrf) {
#pragma unroll
                for (int cf = 0; cf < 2; ++cf) {
                    const int col = cf * 16 + l15;
                    const float bb = bias[h * DH_ + col];
#pragma unroll
                    for (int e = 0; e < 4; ++e)
                        dst[rowbase + rf * 16 + r0 + e][col] = acc[rf][cf][e] + bb;
                }
            }
        }
    }
    __syncthreads();

    // ---- attention phase: i = tid>>2 (q-row), jg = tid&3 (j stride-4) ----
    const int i = tid >> 2, jg = tid & 3;
    const float sc = 0.17677669529663687f;   // 1/sqrt(32)
    float p[32];
    float mx = -1e30f;
#pragma unroll
    for (int jj = 0; jj < 32; ++jj) {
        const int j = jg + jj * 4;
        f32x4 a4 = {0.f, 0.f, 0.f, 0.f};
#pragma unroll
        for (int k4 = 0; k4 < 8; ++k4) {
            f32x4 q  = *(const f32x4*)&Qs[i][k4 * 4];
            f32x4 kv = *(const f32x4*)&Ks[j][k4 * 4];
            a4 += q * kv;
        }
        const float s = (a4[0] + a4[1] + a4[2] + a4[3]) * sc;
        p[jj] = s;
        mx = fmaxf(mx, s);
    }
    mx = fmaxf(mx, __shfl_xor(mx, 1));
    mx = fmaxf(mx, __shfl_xor(mx, 2));
    float sum = 0.f;
#pragma unroll
    for (int jj = 0; jj < 32; ++jj) {
        p[jj] = __expf(p[jj] - mx);
        sum += p[jj];
    }
    sum += __shfl_xor(sum, 1);
    sum += __shfl_xor(sum, 2);
    const float inv = 1.f / sum;

    f32x4 o[8] = {};
#pragma unroll
    for (int jj = 0; jj < 32; ++jj) {
        const int j = jg + jj * 4;
        const float pv = p[jj];
#pragma unroll
        for (int d4 = 0; d4 < 8; ++d4) {
            f32x4 vv = *(const f32x4*)&Vs[j][d4 * 4];
            o[d4] += vv * pv;
        }
    }
    // reduce partial O across the 4 jg lanes; lane jg stores dims jg*8..+8
#pragma unroll
    for (int d4 = 0; d4 < 8; ++d4) {
#pragma unroll
        for (int e = 0; e < 4; ++e) {
            o[d4][e] += __shfl_xor(o[d4][e], 1);
            o[d4][e] += __shfl_xor(o[d4][e], 2);
        }
    }
    const int d0 = jg * 2;
    s16x8 ov;
#pragma unroll
    for (int e = 0; e < 4; ++e) {
        ov[e]     = (short)f2b(o[d0][e] * inv);
        ov[4 + e] = (short)f2b(o[d0 + 1][e] * inv);
    }
    *(s16x8*)&Ob[(size_t)(b * S_ + i) * D_ + h * DH_ + jg * 8] = ov;
}

// ---------------------------------------------------------------------------
// Fused Wo-GEMM + residual + LN1. 32 blocks (M-tile 16, full N=256), 512 thr
// = 8 waves; wave w owns cols w*32..+31. Register-streaming MFMA from L2
// (K=256: 8 unrolled steps, no staging/barriers), C-tile in LDS, block LN.
// ---------------------------------------------------------------------------
__global__ __launch_bounds__(512) void woln_k(
    const ushort_t* __restrict__ A,   // Ob [T][256] bf16
    const ushort_t* __restrict__ BT,  // WoT [256 n][256 k] bf16
    const float* __restrict__ bias,   // bo
    float* __restrict__ X, ushort_t* __restrict__ Xb,
    const float* __restrict__ lns, const float* __restrict__ lnb)
{
    __shared__ float Ct[16][264];
    const int tid = threadIdx.x;
    const int m0 = blockIdx.x * 16;
    const int w = tid >> 6, lane = tid & 63;
    const int l15 = lane & 15, kg = (lane >> 4) * 8;

    f32x4 acc0 = {0.f,0.f,0.f,0.f}, acc1 = acc0;
    const ushort_t* Abase = A  + (size_t)(m0 + l15) * D_;
    const ushort_t* B0    = BT + (size_t)(w * 32 + l15) * D_;
    const ushort_t* B1    = BT + (size_t)(w * 32 + 16 + l15) * D_;
#pragma unroll
    for (int kk = 0; kk < 8; ++kk) {
        const int k0 = kk * 32 + kg;
        s16x8 af = *(const s16x8*)&Abase[k0];
        s16x8 b0 = *(const s16x8*)&B0[k0];
        s16x8 b1 = *(const s16x8*)&B1[k0];
        acc0 = __builtin_amdgcn_mfma_f32_16x16x32_bf16(af, b0, acc0, 0, 0, 0);
        acc1 = __builtin_amdgcn_mfma_f32_16x16x32_bf16(af, b1, acc1, 0, 0, 0);
    }
    const int r0 = (lane >> 4) * 4;
#pragma unroll
    for (int e = 0; e < 4; ++e) {
        Ct[r0 + e][w * 32 + l15]      = acc0[e];
        Ct[r0 + e][w * 32 + 16 + l15] = acc1[e];
    }
    __syncthreads();

    // LN: row = tid>>5 (16 rows), 32 threads/row, 8 cols each
    const int row = tid >> 5, cg = tid & 31;
    const int grow = m0 + row, c0 = cg * 8;
    float a[8];
    float sum = 0.f;
#pragma unroll
    for (int e = 0; e < 8; ++e) {
        a[e] = Ct[row][c0 + e] + X[(size_t)grow * D_ + c0 + e] + bias[c0 + e];
        sum += a[e];
    }
    sum += __shfl_xor(sum, 1);  sum += __shfl_xor(sum, 2);
    sum += __shfl_xor(sum, 4);  sum += __shfl_xor(sum, 8);
    sum += __shfl_xor(sum, 16);
    const float mean = sum * (1.f / D_);
    float vs = 0.f;
#pragma unroll
    for (int e = 0; e < 8; ++e) { const float d = a[e] - mean; vs += d * d; }
    vs += __shfl_xor(vs, 1);  vs += __shfl_xor(vs, 2);
    vs += __shfl_xor(vs, 4);  vs += __shfl_xor(vs, 8);
    vs += __shfl_xor(vs, 16);
    const float rstd = rsqrtf(vs * (1.f / D_) + 1e-5f);
    f32x4 y0, y1; u16x4 yb0, yb1;
#pragma unroll
    for (int e = 0; e < 4; ++e) {
        const float ya = (a[e] - mean) * rstd * lns[c0 + e] + lnb[c0 + e];
        const float yc = (a[e + 4] - mean) * rstd * lns[c0 + 4 + e] + lnb[c0 + 4 + e];
        y0[e] = ya; yb0[e] = f2b(ya);
        y1[e] = yc; yb1[e] = f2b(yc);
    }
    *(f32x4*)&X [(size_t)grow * D_ + c0]     = y0;
    *(f32x4*)&X [(size_t)grow * D_ + c0 + 4] = y1;
    *(u16x4*)&Xb[(size_t)grow * D_ + c0]     = yb0;
    *(u16x4*)&Xb[(size_t)grow * D_ + c0 + 4] = yb1;
}

// ---------------------------------------------------------------------------
// prep: blocks [0,512) = embedding gather (+bf16 X and emb); [512,3072) =
// weight transpose fp32 [R][C] -> bf16 [C][R] in 32x32 LDS tiles.
// ---------------------------------------------------------------------------
__global__ __launch_bounds__(256) void prep_k(const int* __restrict__ xt,
    const float* __restrict__ emb, float* __restrict__ X,
    ushort_t* __restrict__ Xb, ushort_t* __restrict__ embB,
    const float* __restrict__ Wq, const float* __restrict__ Wk,
    const float* __restrict__ Wv, const float* __restrict__ Wo,
    const float* __restrict__ W1, const float* __restrict__ W2,
    ushort_t* __restrict__ WT, ushort_t* __restrict__ W1T, ushort_t* __restrict__ W2T)
{
    __shared__ float Tl[32][33];
    const int tid = threadIdx.x;
    if (blockIdx.x < 512) {
        const int idx = blockIdx.x * 256 + tid;       // < T_*D_ == V_*D_
        const int t = idx >> 8, d = idx & 255;
        const float v = emb[(size_t)xt[t] * D_ + d];
        X[idx]  = v;
        Xb[idx] = f2b(v);
        embB[idx] = f2b(emb[idx]);
        return;
    }
    const int id = blockIdx.x - 512;
    const int l  = id >= 1280 ? 1 : 0;
    const int t  = id - l * 1280;
    const float* src; ushort_t* dst; int R, C, rt, ct;
    if (t < 256) {
        const int kind = t >> 6, tl = t & 63;
        const float* s0 = (kind == 0) ? Wq : (kind == 1) ? Wk : (kind == 2) ? Wv : Wo;
        src = s0 + (size_t)l * (D_ * D_);
        dst = WT + (size_t)l * (4 * D_ * D_) + (size_t)kind * (D_ * D_);
        R = D_; C = D_; rt = tl >> 3; ct = tl & 7;
    } else if (t < 768) {
        const int tl = t - 256;
        src = W1 + (size_t)l * (D_ * FF_); dst = W1T + (size_t)l * (D_ * FF_);
        R = D_; C = FF_; rt = tl >> 6; ct = tl & 63;
    } else {
        const int tl = t - 768;
        src = W2 + (size_t)l * (FF_ * D_); dst = W2T + (size_t)l * (FF_ * D_);
        R = FF_; C = D_; rt = tl >> 3; ct = tl & 7;
    }
    const int r = tid >> 3, c4 = (tid & 7) * 4;
    f32x4 v = *(const f32x4*)&src[(size_t)(rt * 32 + r) * C + ct * 32 + c4];
    Tl[r][c4] = v[0]; Tl[r][c4 + 1] = v[1]; Tl[r][c4 + 2] = v[2]; Tl[r][c4 + 3] = v[3];
    __syncthreads();
    u16x4 ov;
    ov[0] = f2b(Tl[c4 + 0][r]); ov[1] = f2b(Tl[c4 + 1][r]);
    ov[2] = f2b(Tl[c4 + 2][r]); ov[3] = f2b(Tl[c4 + 3][r]);
    *(u16x4*)&dst[(size_t)(ct * 32 + r) * R + rt * 32 + c4] = ov;
}

// ---------------------------------------------------------------------------
// x = LN(x + sum parts + bias) * s + b ; writes fp32 X and bf16 Xb.
// nparts in {2,4}: parts 0-1 in p0[0],p0[TD]; parts 2-3 in p1.
// ---------------------------------------------------------------------------
__global__ __launch_bounds__(256) void add_ln_k(
    const float* __restrict__ p0, const float* __restrict__ p1, int nparts,
    const float* __restrict__ bias, float* __restrict__ X,
    ushort_t* __restrict__ Xb, const float* __restrict__ s,
    const float* __restrict__ b)
{
    __shared__ float red[4];
    const int row = blockIdx.x, tid = threadIdx.x;
    const size_t off = (size_t)row * D_ + tid;
    const size_t TD = (size_t)T_ * D_;
    float a = X[off] + bias[tid] + p0[off];
    if (nparts >= 2) a += p0[TD + off];
    if (nparts == 4) a += p1[off] + p1[TD + off];

    float ws_ = waveReduceSum(a);
    if ((tid & 63) == 0) red[tid >> 6] = ws_;
    __syncthreads();
    const float mean = (red[0] + red[1] + red[2] + red[3]) * (1.f / D_);
    __syncthreads();
    const float d = a - mean;
    float vs = waveReduceSum(d * d);
    if ((tid & 63) == 0) red[tid >> 6] = vs;
    __syncthreads();
    const float var = (red[0] + red[1] + red[2] + red[3]) * (1.f / D_);
    const float y = d * rsqrtf(var + 1e-5f) * s[tid] + b[tid];
    X[off]  = y;
    Xb[off] = f2b(y);
}

// ---------------------------------------------------------------------------
// Fused final softmax + broadcast: block = (token t, quarter of row-range).
// ---------------------------------------------------------------------------
__global__ __launch_bounds__(256) void bcast_k(const float* __restrict__ Lg,
    const float* __restrict__ temp, float* __restrict__ out)
{
    __shared__ float row[V_];
    __shared__ float red[4];
    const int blk = blockIdx.x, t = blk >> 2, quarter = blk & 3;
    const int tid = threadIdx.x;
    const float rT = 1.f / temp[0];
    const float l0 = Lg[(size_t)t * V_ + tid] * rT;
    const float l1 = Lg[(size_t)t * V_ + 256 + tid] * rT;
    float m = waveReduceMax(fmaxf(l0, l1));
    if ((tid & 63) == 0) red[tid >> 6] = m;
    __syncthreads();
    m = fmaxf(fmaxf(red[0], red[1]), fmaxf(red[2], red[3]));
    __syncthreads();
    const float e0 = __expf(l0 - m), e1 = __expf(l1 - m);
    float sblk = waveReduceSum(e0 + e1);
    if ((tid & 63) == 0) red[tid >> 6] = sblk;
    __syncthreads();
    const float inv = 1.f / (red[0] + red[1] + red[2] + red[3]);
    row[tid] = e0 * inv;
    row[tid + 256] = e1 * inv;
    __syncthreads();

    const int c = tid & 127, ihalf = tid >> 7;
    f32x4 v = *(const f32x4*)&row[c * 4];
    f32x4* dst = (f32x4*)out + (size_t)t * V_ * (V_ / 4);
#pragma unroll 4
    for (int r = 0; r < 64; ++r) {
        const int i = quarter * 128 + ihalf + r * 2;
        __builtin_nontemporal_store(v, &dst[(size_t)i * (V_ / 4) + c]);
    }
}

// ---------------------------------------------------------------------------
// Host launch. ws layout (bytes), total 10.0 MB (unchanged from round 6):
//   0        X     fp32 512KB
//   524288   PartA fp32 2x512KB (split-K parts 0-1; alias Lg at end)
//   1572864  PartB fp32 2x512KB (alias: Ob dead during W2 GEMM)
//   2359296  Ob    bf16 256KB   (inside PartB range; disjoint lifetime)
//   2621440  Xb    bf16 256KB
//   2883584  Ffb   bf16 2MB
//   4980736  embB  bf16 256KB
//   5242880  WT    bf16 1MB
//   6291456  W1T   bf16 2MB
//   8388608  W2T   bf16 2MB   -> end 10485760
// ---------------------------------------------------------------------------
extern "C" void kernel_launch(void* const* d_in, const int* in_sizes, int n_in,
                              void* d_out, int out_size, void* d_ws, size_t ws_size,
                              hipStream_t stream)
{
    const int*   x_t  = (const int*)  d_in[0];
    const float* emb  = (const float*)d_in[1];
    const float* temp = (const float*)d_in[2];
    const float* Wq   = (const float*)d_in[3];
    const float* Wk   = (const float*)d_in[4];
    const float* Wv   = (const float*)d_in[5];
    const float* Wo   = (const float*)d_in[6];
    const float* bq   = (const float*)d_in[7];
    const float* bk   = (const float*)d_in[8];
    const float* bv   = (const float*)d_in[9];
    const float* bo   = (const float*)d_in[10];
    const float* W1   = (const float*)d_in[11];
    const float* b1   = (const float*)d_in[12];
    const float* W2   = (const float*)d_in[13];
    const float* b2   = (const float*)d_in[14];
    const float* ln1s = (const float*)d_in[15];
    const float* ln1b = (const float*)d_in[16];
    const float* ln2s = (const float*)d_in[17];
    const float* ln2b = (const float*)d_in[18];

    float* out = (float*)d_out;
    char*  wsb = (char*)d_ws;

    float*    X     = (float*)   (wsb + 0);
    float*    PartA = (float*)   (wsb + 524288);
    float*    Lg    = PartA;                        // alias (disjoint lifetime)
    float*    PartB = (float*)   (wsb + 1572864);
    ushort_t* Ob    = (ushort_t*)(wsb + 2359296);
    ushort_t* Xb    = (ushort_t*)(wsb + 2621440);
    ushort_t* Ffb   = (ushort_t*)(wsb + 2883584);
    ushort_t* embB  = (ushort_t*)(wsb + 4980736);
    ushort_t* WT    = (ushort_t*)(wsb + 5242880);
    ushort_t* W1T   = (ushort_t*)(wsb + 6291456);
    ushort_t* W2T   = (ushort_t*)(wsb + 8388608);

    prep_k<<<3072, 256, 0, stream>>>(x_t, emb, X, Xb, embB,
                                     Wq, Wk, Wv, Wo, W1, W2, WT, W1T, W2T);

    for (int l = 0; l < L_; ++l) {
        const ushort_t* WTl  = WT  + (size_t)l * (4 * D_ * D_);
        const ushort_t* W1Tl = W1T + (size_t)l * (D_ * FF_);
        const ushort_t* W2Tl = W2T + (size_t)l * (FF_ * D_);

        // QKV projection + attention fused: 32 blocks (b,h)
        qkvattn_k<<<32, 512, 0, stream>>>(
            Xb, WTl, bq + l * D_, bk + l * D_, bv + l * D_, Ob);

        // Wo GEMM + residual + LN1 fused: 32 blocks (M-tile 16)
        woln_k<<<32, 512, 0, stream>>>(Ob, WTl + 3 * D_ * D_, bo + l * D_,
                                       X, Xb, ln1s + l * D_, ln1b + l * D_);

        // relu(x @ W1 + b1) -> Ffb (bf16)
        mgemm_k<1, 1, 1><<<dim3(32, 8, 1), 256, 0, stream>>>(
            Xb, W1Tl, b1 + l * FF_, nullptr, nullptr, Ffb, T_, FF_, D_, D_);

        // Ffb @ W2 split-K z=4 -> PartA[0..1] + PartB[0..1]; b2 in add_ln
        mgemm_k<0, 0, 0><<<dim3(4, 8, 4), 256, 0, stream>>>(
            Ffb, W2Tl, nullptr, PartA, PartB, nullptr, T_, D_, FF_, FF_ / 4);
        add_ln_k<<<T_, 256, 0, stream>>>(PartA, PartB, 4, b2 + l * D_,
                                         X, Xb, ln2s + l * D_, ln2b + l * D_);
    }

    // logits = Xb @ embB^T -> Lg (fp32)
    mgemm_k<0, 0, 0><<<dim3(8, 8, 1), 256, 0, stream>>>(
        Xb, embB, nullptr, Lg, nullptr, nullptr, T_, V_, D_, D_);

    bcast_k<<<T_ * 4, 256, 0, stream>>>(Lg, temp, out);
}

// Round 9
// 195.788 us; speedup vs baseline: 1.0281x; 1.0281x over previous
//
#include <hip/hip_runtime.h>
#include <math.h>

// Problem constants (SemanticAwareTransitions_9826885173968)
#define V_  512
#define D_  256
#define H_  8
#define DH_ 32
#define FF_ 2048
#define L_  2
#define B_  4
#define S_  128
#define T_  (B_*S_)   // 512 tokens

typedef float f32x4 __attribute__((ext_vector_type(4)));
typedef short s16x8 __attribute__((ext_vector_type(8)));
typedef unsigned short u16x4 __attribute__((ext_vector_type(4)));
typedef unsigned short ushort_t;

// fp32 -> bf16 bits, round-to-nearest-even
__device__ __forceinline__ ushort_t f2b(float f) {
    unsigned int u = __builtin_bit_cast(unsigned int, f);
    u += 0x7FFFu + ((u >> 16) & 1u);
    return (ushort_t)(u >> 16);
}
__device__ __forceinline__ float b2f(ushort_t h) {
    unsigned int u = ((unsigned int)h) << 16;
    return __builtin_bit_cast(float, u);
}

__device__ __forceinline__ float waveReduceSum(float v) {
#pragma unroll
    for (int off = 32; off > 0; off >>= 1) v += __shfl_xor(v, off);
    return v;
}
__device__ __forceinline__ float waveReduceMax(float v) {
#pragma unroll
    for (int off = 32; off > 0; off >>= 1) v = fmaxf(v, __shfl_xor(v, off));
    return v;
}

// ---------------------------------------------------------------------------
// Plain bf16 MFMA GEMM (64x64 tile, BK=64, 4 waves), round-6 proven body:
// double-buffered, lgkmcnt-only barrier (global loads in flight across it).
// Used for Wo (z=2) and W2 (z=2) whose A inputs are already bf16.
// mfma_f32_16x16x32_bf16 D-layout: col=lane&15, row=(lane>>4)*4+reg.
// ---------------------------------------------------------------------------
template<int RELU, int OUTB, int BIAS>
__global__ __launch_bounds__(256) void mgemm_k(const ushort_t* __restrict__ A,
    const ushort_t* __restrict__ BT, const float* __restrict__ bias,
    float* __restrict__ Cf0, ushort_t* __restrict__ Cb,
    int M, int N, int K, int kChunk)
{
    __shared__ ushort_t Al[2][64][72];
    __shared__ ushort_t Bl[2][64][72];
    const int tid  = threadIdx.x;
    const int m0   = blockIdx.y * 64, n0 = blockIdx.x * 64;
    const int z    = blockIdx.z;
    const int kBegin = z * kChunk, kSteps = kChunk / 64;
    float* Cf = Cf0 ? Cf0 + (size_t)z * M * N : nullptr;
    const int lane = tid & 63, w = tid >> 6;
    const int srow = tid >> 2, sseg = (tid & 3) * 16;
    const int l15  = lane & 15,  kg = (lane >> 4) * 8;

    f32x4 acc0 = {0.f,0.f,0.f,0.f}, acc1 = acc0, acc2 = acc0, acc3 = acc0;

    const ushort_t* Aptr = &A [(size_t)(m0 + srow) * K + kBegin + sseg];
    const ushort_t* Bptr = &BT[(size_t)(n0 + srow) * K + kBegin + sseg];

    s16x8 av0 = *(const s16x8*)Aptr,  av1 = *(const s16x8*)(Aptr + 8);
    s16x8 bv0 = *(const s16x8*)Bptr,  bv1 = *(const s16x8*)(Bptr + 8);
    *(s16x8*)&Al[0][srow][sseg]     = av0;
    *(s16x8*)&Al[0][srow][sseg + 8] = av1;
    *(s16x8*)&Bl[0][srow][sseg]     = bv0;
    *(s16x8*)&Bl[0][srow][sseg + 8] = bv1;

    for (int kt = 0; kt < kSteps; ++kt) {
        const int cur = kt & 1;
        const bool more = (kt + 1 < kSteps);
        if (more) {
            const size_t o = (size_t)(kt + 1) * 64;
            av0 = *(const s16x8*)(Aptr + o);     av1 = *(const s16x8*)(Aptr + o + 8);
            bv0 = *(const s16x8*)(Bptr + o);     bv1 = *(const s16x8*)(Bptr + o + 8);
        }
        asm volatile("s_waitcnt lgkmcnt(0)\n\ts_barrier" ::: "memory");

        s16x8 b0  = *(const s16x8*)&Bl[cur][w * 16 + l15][kg];
        s16x8 b1  = *(const s16x8*)&Bl[cur][w * 16 + l15][kg + 32];
        s16x8 a00 = *(const s16x8*)&Al[cur][     l15][kg];
        s16x8 a01 = *(const s16x8*)&Al[cur][     l15][kg + 32];
        s16x8 a10 = *(const s16x8*)&Al[cur][16 + l15][kg];
        s16x8 a11 = *(const s16x8*)&Al[cur][16 + l15][kg + 32];
        s16x8 a20 = *(const s16x8*)&Al[cur][32 + l15][kg];
        s16x8 a21 = *(const s16x8*)&Al[cur][32 + l15][kg + 32];
        s16x8 a30 = *(const s16x8*)&Al[cur][48 + l15][kg];
        s16x8 a31 = *(const s16x8*)&Al[cur][48 + l15][kg + 32];
        acc0 = __builtin_amdgcn_mfma_f32_16x16x32_bf16(a00, b0, acc0, 0, 0, 0);
        acc1 = __builtin_amdgcn_mfma_f32_16x16x32_bf16(a10, b0, acc1, 0, 0, 0);
        acc2 = __builtin_amdgcn_mfma_f32_16x16x32_bf16(a20, b0, acc2, 0, 0, 0);
        acc3 = __builtin_amdgcn_mfma_f32_16x16x32_bf16(a30, b0, acc3, 0, 0, 0);
        acc0 = __builtin_amdgcn_mfma_f32_16x16x32_bf16(a01, b1, acc0, 0, 0, 0);
        acc1 = __builtin_amdgcn_mfma_f32_16x16x32_bf16(a11, b1, acc1, 0, 0, 0);
        acc2 = __builtin_amdgcn_mfma_f32_16x16x32_bf16(a21, b1, acc2, 0, 0, 0);
        acc3 = __builtin_amdgcn_mfma_f32_16x16x32_bf16(a31, b1, acc3, 0, 0, 0);

        if (more) {
            *(s16x8*)&Al[cur ^ 1][srow][sseg]     = av0;
            *(s16x8*)&Al[cur ^ 1][srow][sseg + 8] = av1;
            *(s16x8*)&Bl[cur ^ 1][srow][sseg]     = bv0;
            *(s16x8*)&Bl[cur ^ 1][srow][sseg + 8] = bv1;
        }
    }

    const int col = n0 + w * 16 + l15;
    const float bb = BIAS ? bias[col] : 0.f;
    f32x4 accs[4] = {acc0, acc1, acc2, acc3};
#pragma unroll
    for (int r = 0; r < 4; ++r) {
#pragma unroll
        for (int e = 0; e < 4; ++e) {
            const int row = m0 + r * 16 + (lane >> 4) * 4 + e;
            float v = accs[r][e] + bb;
            if (RELU) v = fmaxf(v, 0.f);
            if (OUTB) Cb[(size_t)row * N + col] = f2b(v);
            else      Cf[(size_t)row * N + col] = v;
        }
    }
}

// ---------------------------------------------------------------------------
// Fused LN+GEMM body: A = LN(Xres + addb + p0[0] + p0[TD]) computed per block
// (redundant across n-tiles, deterministic), bf16 A-tile in LDS; K = D_ = 256
// always. B double-buffered from global (lgkmcnt-only barrier). NPARTS==0:
// A = bf16(Xres) (no LN; embed path). Xout != nullptr: also store fp32 LN
// output (designated blocks only) for the next residual. LN stats via fp32
// sum/sumsq (E[x^2]-mean^2) -- one pass, a[] kept in registers.
// ---------------------------------------------------------------------------
template<int NPARTS, int RELU, int OUTB, int BIAS>
__device__ __forceinline__ void gemmln_body(
    const float* __restrict__ Xres, const float* __restrict__ p0,
    const float* __restrict__ addb, const float* __restrict__ lns,
    const float* __restrict__ lnb,
    const ushort_t* __restrict__ BT, const float* __restrict__ gbias,
    float* __restrict__ Cf, ushort_t* __restrict__ Cb,
    float* __restrict__ Xout, int m0, int n0, int N)
{
    __shared__ ushort_t At[64][264];       // bf16 A tile, 2-way-bank-free pad
    __shared__ ushort_t Bl[2][64][72];
    const int tid = threadIdx.x;
    const int lane = tid & 63, w = tid >> 6;
    const int l15 = lane & 15, kg = (lane >> 4) * 8;
    const size_t TD = (size_t)T_ * D_;

    {   // ---- LN / cast prologue: thread = (row r, quarter q) ----
        const int r = tid >> 2, q = tid & 3;
        const int grow = m0 + r;
        const float* xrow = Xres + (size_t)grow * D_;
        f32x4 a[16];
        float s = 0.f, s2 = 0.f;
#pragma unroll
        for (int i = 0; i < 16; ++i) {
            const int c = (i << 4) + (q << 2);   // lanes q=0..3 -> 64B runs
            f32x4 v = *(const f32x4*)&xrow[c];
            if (NPARTS >= 2) {
                v += *(const f32x4*)&addb[c];
                v += *(const f32x4*)&p0[(size_t)grow * D_ + c];
                v += *(const f32x4*)&p0[TD + (size_t)grow * D_ + c];
            }
            a[i] = v;
            s  += v[0] + v[1] + v[2] + v[3];
            s2 += v[0]*v[0] + v[1]*v[1] + v[2]*v[2] + v[3]*v[3];
        }
        float mean = 0.f, rstd = 1.f;
        if (NPARTS) {
            s  += __shfl_xor(s, 1);  s  += __shfl_xor(s, 2);
            s2 += __shfl_xor(s2, 1); s2 += __shfl_xor(s2, 2);
            mean = s * (1.f / D_);
            const float var = s2 * (1.f / D_) - mean * mean;
            rstd = rsqrtf(var + 1e-5f);
        }
        const bool wr = (Xout != nullptr);
#pragma unroll
        for (int i = 0; i < 16; ++i) {
            const int c = (i << 4) + (q << 2);
            f32x4 y;
            if (NPARTS) {
#pragma unroll
                for (int e = 0; e < 4; ++e)
                    y[e] = (a[i][e] - mean) * rstd * lns[c + e] + lnb[c + e];
            } else y = a[i];
            u16x4 yb;
#pragma unroll
            for (int e = 0; e < 4; ++e) yb[e] = f2b(y[e]);
            *(u16x4*)&At[r][c] = yb;
            if (wr) *(f32x4*)&Xout[(size_t)grow * D_ + c] = y;
        }
    }

    // ---- GEMM: K = 256, 4 steps of BK=64; B dbuf, A from LDS tile ----
    const int srow = tid >> 2, sseg = (tid & 3) * 16;
    const ushort_t* Bptr = &BT[(size_t)(n0 + srow) * D_ + sseg];
    s16x8 bv0 = *(const s16x8*)Bptr, bv1 = *(const s16x8*)(Bptr + 8);
    *(s16x8*)&Bl[0][srow][sseg]     = bv0;
    *(s16x8*)&Bl[0][srow][sseg + 8] = bv1;

    f32x4 acc0 = {0.f,0.f,0.f,0.f}, acc1 = acc0, acc2 = acc0, acc3 = acc0;
#pragma unroll
    for (int kt = 0; kt < 4; ++kt) {
        const int cur = kt & 1;
        if (kt < 3) {
            const size_t o = (size_t)(kt + 1) * 64;
            bv0 = *(const s16x8*)(Bptr + o);  bv1 = *(const s16x8*)(Bptr + o + 8);
        }
        // covers At+Bl[0] visibility at kt=0; Bl dbuf handoff afterwards
        asm volatile("s_waitcnt lgkmcnt(0)\n\ts_barrier" ::: "memory");

        const int k0 = kt * 64;
        s16x8 b0  = *(const s16x8*)&Bl[cur][w * 16 + l15][kg];
        s16x8 b1  = *(const s16x8*)&Bl[cur][w * 16 + l15][kg + 32];
        s16x8 a00 = *(const s16x8*)&At[     l15][k0 + kg];
        s16x8 a01 = *(const s16x8*)&At[     l15][k0 + kg + 32];
        s16x8 a10 = *(const s16x8*)&At[16 + l15][k0 + kg];
        s16x8 a11 = *(const s16x8*)&At[16 + l15][k0 + kg + 32];
        s16x8 a20 = *(const s16x8*)&At[32 + l15][k0 + kg];
        s16x8 a21 = *(const s16x8*)&At[32 + l15][k0 + kg + 32];
        s16x8 a30 = *(const s16x8*)&At[48 + l15][k0 + kg];
        s16x8 a31 = *(const s16x8*)&At[48 + l15][k0 + kg + 32];
        acc0 = __builtin_amdgcn_mfma_f32_16x16x32_bf16(a00, b0, acc0, 0, 0, 0);
        acc1 = __builtin_amdgcn_mfma_f32_16x16x32_bf16(a10, b0, acc1, 0, 0, 0);
        acc2 = __builtin_amdgcn_mfma_f32_16x16x32_bf16(a20, b0, acc2, 0, 0, 0);
        acc3 = __builtin_amdgcn_mfma_f32_16x16x32_bf16(a30, b0, acc3, 0, 0, 0);
        acc0 = __builtin_amdgcn_mfma_f32_16x16x32_bf16(a01, b1, acc0, 0, 0, 0);
        acc1 = __builtin_amdgcn_mfma_f32_16x16x32_bf16(a11, b1, acc1, 0, 0, 0);
        acc2 = __builtin_amdgcn_mfma_f32_16x16x32_bf16(a21, b1, acc2, 0, 0, 0);
        acc3 = __builtin_amdgcn_mfma_f32_16x16x32_bf16(a31, b1, acc3, 0, 0, 0);

        if (kt < 3) {
            *(s16x8*)&Bl[cur ^ 1][srow][sseg]     = bv0;
            *(s16x8*)&Bl[cur ^ 1][srow][sseg + 8] = bv1;
        }
    }

    const int col = n0 + w * 16 + l15;
    const float bb = BIAS ? gbias[col] : 0.f;
    f32x4 accs[4] = {acc0, acc1, acc2, acc3};
#pragma unroll
    for (int r = 0; r < 4; ++r) {
#pragma unroll
        for (int e = 0; e < 4; ++e) {
            const int row = m0 + r * 16 + (lane >> 4) * 4 + e;
            float v = accs[r][e] + bb;
            if (RELU) v = fmaxf(v, 0.f);
            if (OUTB) Cb[(size_t)row * N + col] = f2b(v);
            else      Cf[(size_t)row * N + col] = v;
        }
    }
}

// QKV (+optional fused LN2 of previous layer). grid (4, 8, 3).
template<int NPARTS>
__global__ __launch_bounds__(256) void qkvln_k(
    const float* __restrict__ Xres, const float* __restrict__ p0,
    const float* __restrict__ addb, const float* __restrict__ lns,
    const float* __restrict__ lnb, const ushort_t* __restrict__ WT,
    const float* __restrict__ bq, const float* __restrict__ bk,
    const float* __restrict__ bv,
    ushort_t* __restrict__ Qb, ushort_t* __restrict__ Kb,
    ushort_t* __restrict__ Vb, float* __restrict__ Xout)
{
    const int z = blockIdx.z;
    const ushort_t* bt = WT + (size_t)z * (D_ * D_);
    const float* bias; ushort_t* outp;
    if (z == 0)      { bias = bq; outp = Qb; }
    else if (z == 1) { bias = bk; outp = Kb; }
    else             { bias = bv; outp = Vb; }
    float* xo = (z == 0 && blockIdx.x == 0) ? Xout : nullptr;
    gemmln_body<NPARTS, 0, 1, 1>(Xres, p0, addb, lns, lnb, bt, bias,
                                 nullptr, outp, xo,
                                 blockIdx.y * 64, blockIdx.x * 64, D_);
}

// W1 + fused LN1. grid (32, 8).
__global__ __launch_bounds__(256) void w1ln_k(
    const float* __restrict__ Xres, const float* __restrict__ p0,
    const float* __restrict__ addb, const float* __restrict__ lns,
    const float* __restrict__ lnb, const ushort_t* __restrict__ W1T,
    const float* __restrict__ b1, ushort_t* __restrict__ Ffb,
    float* __restrict__ Xout)
{
    float* xo = (blockIdx.x == 0) ? Xout : nullptr;
    gemmln_body<2, 1, 1, 1>(Xres, p0, addb, lns, lnb, W1T, b1,
                            nullptr, Ffb, xo,
                            blockIdx.y * 64, blockIdx.x * 64, FF_);
}

// logits + fused LN2 (layer 1). grid (8, 8).
__global__ __launch_bounds__(256) void logitsln_k(
    const float* __restrict__ Xres, const float* __restrict__ p0,
    const float* __restrict__ addb, const float* __restrict__ lns,
    const float* __restrict__ lnb, const ushort_t* __restrict__ embB,
    float* __restrict__ Lg)
{
    gemmln_body<2, 0, 0, 0>(Xres, p0, addb, lns, lnb, embB, nullptr,
                            Lg, nullptr, nullptr,
                            blockIdx.y * 64, blockIdx.x * 64, V_);
}

// ---------------------------------------------------------------------------
// prep: blocks [0,512) = embedding gather (fp32 X + bf16 emb); [512,3072) =
// weight transpose fp32 [R][C] -> bf16 [C][R] in 32x32 LDS tiles.
// ---------------------------------------------------------------------------
__global__ __launch_bounds__(256) void prep_k(const int* __restrict__ xt,
    const float* __restrict__ emb, float* __restrict__ X,
    ushort_t* __restrict__ embB,
    const float* __restrict__ Wq, const float* __restrict__ Wk,
    const float* __restrict__ Wv, const float* __restrict__ Wo,
    const float* __restrict__ W1, const float* __restrict__ W2,
    ushort_t* __restrict__ WT, ushort_t* __restrict__ W1T, ushort_t* __restrict__ W2T)
{
    __shared__ float Tl[32][33];
    const int tid = threadIdx.x;
    if (blockIdx.x < 512) {
        const int idx = blockIdx.x * 256 + tid;       // < T_*D_ == V_*D_
        const int t = idx >> 8, d = idx & 255;
        X[idx]  = emb[(size_t)xt[t] * D_ + d];
        embB[idx] = f2b(emb[idx]);
        return;
    }
    const int id = blockIdx.x - 512;
    const int l  = id >= 1280 ? 1 : 0;
    const int t  = id - l * 1280;
    const float* src; ushort_t* dst; int R, C, rt, ct;
    if (t < 256) {
        const int kind = t >> 6, tl = t & 63;
        const float* s0 = (kind == 0) ? Wq : (kind == 1) ? Wk : (kind == 2) ? Wv : Wo;
        src = s0 + (size_t)l * (D_ * D_);
        dst = WT + (size_t)l * (4 * D_ * D_) + (size_t)kind * (D_ * D_);
        R = D_; C = D_; rt = tl >> 3; ct = tl & 7;
    } else if (t < 768) {
        const int tl = t - 256;
        src = W1 + (size_t)l * (D_ * FF_); dst = W1T + (size_t)l * (D_ * FF_);
        R = D_; C = FF_; rt = tl >> 6; ct = tl & 63;
    } else {
        const int tl = t - 768;
        src = W2 + (size_t)l * (FF_ * D_); dst = W2T + (size_t)l * (FF_ * D_);
        R = FF_; C = D_; rt = tl >> 3; ct = tl & 7;
    }
    const int r = tid >> 3, c4 = (tid & 7) * 4;
    f32x4 v = *(const f32x4*)&src[(size_t)(rt * 32 + r) * C + ct * 32 + c4];
    Tl[r][c4] = v[0]; Tl[r][c4 + 1] = v[1]; Tl[r][c4 + 2] = v[2]; Tl[r][c4 + 3] = v[3];
    __syncthreads();
    u16x4 ov;
    ov[0] = f2b(Tl[c4 + 0][r]); ov[1] = f2b(Tl[c4 + 1][r]);
    ov[2] = f2b(Tl[c4 + 2][r]); ov[3] = f2b(Tl[c4 + 3][r]);
    *(u16x4*)&dst[(size_t)(ct * 32 + r) * R + rt * 32 + c4] = ov;
}

// ---------------------------------------------------------------------------
// Fused attention: one block per (b,h,q-quarter). fp32 math, bf16 I/O.
// (round-6 proven body)
// ---------------------------------------------------------------------------
__global__ __launch_bounds__(256) void attn_k(const ushort_t* __restrict__ Qb,
    const ushort_t* __restrict__ Kb, const ushort_t* __restrict__ Vb,
    ushort_t* __restrict__ Ob)
{
    __shared__ float Qs[32][36], Ks[128][36], Vs[128][36], Ps[32][132];
    const int bh = blockIdx.x, b = bh >> 3, h = bh & 7;
    const int i0 = blockIdx.y * 32;
    const int tid = threadIdx.x;

#pragma unroll
    for (int it = 0; it < 2; ++it) {                 // K,V: 512 8-elem chunks
        const int g = it * 256 + tid;
        const int r = g >> 2, c8 = (g & 3) * 8;
        s16x8 kv = *(const s16x8*)&Kb[(size_t)(b * S_ + r) * D_ + h * DH_ + c8];
        s16x8 vv = *(const s16x8*)&Vb[(size_t)(b * S_ + r) * D_ + h * DH_ + c8];
        f32x4 klo = {b2f((ushort_t)kv[0]), b2f((ushort_t)kv[1]), b2f((ushort_t)kv[2]), b2f((ushort_t)kv[3])};
        f32x4 khi = {b2f((ushort_t)kv[4]), b2f((ushort_t)kv[5]), b2f((ushort_t)kv[6]), b2f((ushort_t)kv[7])};
        f32x4 vlo = {b2f((ushort_t)vv[0]), b2f((ushort_t)vv[1]), b2f((ushort_t)vv[2]), b2f((ushort_t)vv[3])};
        f32x4 vhi = {b2f((ushort_t)vv[4]), b2f((ushort_t)vv[5]), b2f((ushort_t)vv[6]), b2f((ushort_t)vv[7])};
        *(f32x4*)&Ks[r][c8]     = klo;  *(f32x4*)&Ks[r][c8 + 4] = khi;
        *(f32x4*)&Vs[r][c8]     = vlo;  *(f32x4*)&Vs[r][c8 + 4] = vhi;
    }
    if (tid < 128) {                                  // Q: 128 chunks
        const int r = tid >> 2, c8 = (tid & 3) * 8;
        s16x8 qv = *(const s16x8*)&Qb[(size_t)(b * S_ + i0 + r) * D_ + h * DH_ + c8];
        f32x4 qlo = {b2f((ushort_t)qv[0]), b2f((ushort_t)qv[1]), b2f((ushort_t)qv[2]), b2f((ushort_t)qv[3])};
        f32x4 qhi = {b2f((ushort_t)qv[4]), b2f((ushort_t)qv[5]), b2f((ushort_t)qv[6]), b2f((ushort_t)qv[7])};
        *(f32x4*)&Qs[r][c8] = qlo;  *(f32x4*)&Qs[r][c8 + 4] = qhi;
    }
    __syncthreads();

    const int i = tid >> 3, jg = tid & 7;
    const float sc = 0.17677669529663687f;   // 1/sqrt(32)
    float sv[16];
    float mx = -1e30f;
#pragma unroll
    for (int jj = 0; jj < 16; ++jj) {
        const int j = jg + jj * 8;
        f32x4 a4 = {0.f,0.f,0.f,0.f};
#pragma unroll
        for (int kk = 0; kk < 8; ++kk) {
            f32x4 q = *(const f32x4*)&Qs[i][kk * 4];
            f32x4 k = *(const f32x4*)&Ks[j][kk * 4];
            a4 += q * k;
        }
        const float sdot = (a4[0] + a4[1] + a4[2] + a4[3]) * sc;
        sv[jj] = sdot;
        mx = fmaxf(mx, sdot);
    }
    mx = fmaxf(mx, __shfl_xor(mx, 1));
    mx = fmaxf(mx, __shfl_xor(mx, 2));
    mx = fmaxf(mx, __shfl_xor(mx, 4));
    float sum = 0.f;
#pragma unroll
    for (int jj = 0; jj < 16; ++jj) {
        const float e = __expf(sv[jj] - mx);
        Ps[i][jg + jj * 8] = e;
        sum += e;
    }
    sum += __shfl_xor(sum, 1);
    sum += __shfl_xor(sum, 2);
    sum += __shfl_xor(sum, 4);
    const float inv = 1.f / sum;
    __syncthreads();

    const int dg = tid & 7;
    f32x4 o = {0.f,0.f,0.f,0.f};
#pragma unroll 4
    for (int j = 0; j < 128; ++j) {
        const float p = Ps[i][j];
        f32x4 vv = *(const f32x4*)&Vs[j][dg * 4];
        o += vv * p;
    }
    u16x4 ov;
    ov[0] = f2b(o[0] * inv); ov[1] = f2b(o[1] * inv);
    ov[2] = f2b(o[2] * inv); ov[3] = f2b(o[3] * inv);
    *(u16x4*)&Ob[(size_t)(b * S_ + i0 + i) * D_ + h * DH_ + dg * 4] = ov;
}

// ---------------------------------------------------------------------------
// Fused final softmax + broadcast: block = (token t, quarter of row-range).
// ---------------------------------------------------------------------------
__global__ __launch_bounds__(256) void bcast_k(const float* __restrict__ Lg,
    const float* __restrict__ temp, float* __restrict__ out)
{
    __shared__ float row[V_];
    __shared__ float red[4];
    const int blk = blockIdx.x, t = blk >> 2, quarter = blk & 3;
    const int tid = threadIdx.x;
    const float rT = 1.f / temp[0];
    const float l0 = Lg[(size_t)t * V_ + tid] * rT;
    const float l1 = Lg[(size_t)t * V_ + 256 + tid] * rT;
    float m = waveReduceMax(fmaxf(l0, l1));
    if ((tid & 63) == 0) red[tid >> 6] = m;
    __syncthreads();
    m = fmaxf(fmaxf(red[0], red[1]), fmaxf(red[2], red[3]));
    __syncthreads();
    const float e0 = __expf(l0 - m), e1 = __expf(l1 - m);
    float sblk = waveReduceSum(e0 + e1);
    if ((tid & 63) == 0) red[tid >> 6] = sblk;
    __syncthreads();
    const float inv = 1.f / (red[0] + red[1] + red[2] + red[3]);
    row[tid] = e0 * inv;
    row[tid + 256] = e1 * inv;
    __syncthreads();

    const int c = tid & 127, ihalf = tid >> 7;
    f32x4 v = *(const f32x4*)&row[c * 4];
    f32x4* dst = (f32x4*)out + (size_t)t * V_ * (V_ / 4);
#pragma unroll 4
    for (int r = 0; r < 64; ++r) {
        const int i = quarter * 128 + ihalf + r * 2;
        __builtin_nontemporal_store(v, &dst[(size_t)i * (V_ / 4) + c]);
    }
}

// ---------------------------------------------------------------------------
// Host launch. ws layout (bytes), total 10.25 MB:
//   0        XA    fp32 512KB  (embed out; then LN2-L1 out)
//   524288   XB    fp32 512KB  (LN1 outputs; residual ping-pong)
//   1048576  PartA fp32 2x512KB (wo / w2 split-K partials)
//   2097152  Qb    bf16 256KB  \
//   2359296  Kb    bf16 256KB   } Lg (fp32 1MB) aliases QKVO at the end
//   2621440  Vb    bf16 256KB   } (all dead by logits time)
//   2883584  Ob    bf16 256KB  /
//   3145728  Ffb   bf16 2MB
//   5242880  embB  bf16 256KB
//   5505024  WT    bf16 1MB
//   6553600  W1T   bf16 2MB
//   8650752  W2T   bf16 2MB   -> end 10747904
// ---------------------------------------------------------------------------
extern "C" void kernel_launch(void* const* d_in, const int* in_sizes, int n_in,
                              void* d_out, int out_size, void* d_ws, size_t ws_size,
                              hipStream_t stream)
{
    const int*   x_t  = (const int*)  d_in[0];
    const float* emb  = (const float*)d_in[1];
    const float* temp = (const float*)d_in[2];
    const float* Wq   = (const float*)d_in[3];
    const float* Wk   = (const float*)d_in[4];
    const float* Wv   = (const float*)d_in[5];
    const float* Wo   = (const float*)d_in[6];
    const float* bq   = (const float*)d_in[7];
    const float* bk   = (const float*)d_in[8];
    const float* bv   = (const float*)d_in[9];
    const float* bo   = (const float*)d_in[10];
    const float* W1   = (const float*)d_in[11];
    const float* b1   = (const float*)d_in[12];
    const float* W2   = (const float*)d_in[13];
    const float* b2   = (const float*)d_in[14];
    const float* ln1s = (const float*)d_in[15];
    const float* ln1b = (const float*)d_in[16];
    const float* ln2s = (const float*)d_in[17];
    const float* ln2b = (const float*)d_in[18];

    float* out = (float*)d_out;
    char*  wsb = (char*)d_ws;

    float*    XA    = (float*)   (wsb + 0);
    float*    XB    = (float*)   (wsb + 524288);
    float*    PartA = (float*)   (wsb + 1048576);
    ushort_t* Qb    = (ushort_t*)(wsb + 2097152);
    ushort_t* Kb    = (ushort_t*)(wsb + 2359296);
    ushort_t* Vb    = (ushort_t*)(wsb + 2621440);
    ushort_t* Ob    = (ushort_t*)(wsb + 2883584);
    float*    Lg    = (float*)   (wsb + 2097152);   // alias QKVO (dead then)
    ushort_t* Ffb   = (ushort_t*)(wsb + 3145728);
    ushort_t* embB  = (ushort_t*)(wsb + 5242880);
    ushort_t* WT    = (ushort_t*)(wsb + 5505024);
    ushort_t* W1T   = (ushort_t*)(wsb + 6553600);
    ushort_t* W2T   = (ushort_t*)(wsb + 8650752);

    prep_k<<<3072, 256, 0, stream>>>(x_t, emb, XA, embB,
                                     Wq, Wk, Wv, Wo, W1, W2, WT, W1T, W2T);

    // ---- Layer 0 ----
    {
        const ushort_t* WT0  = WT;
        const ushort_t* W1T0 = W1T;
        const ushort_t* W2T0 = W2T;

        qkvln_k<0><<<dim3(4, 8, 3), 256, 0, stream>>>(
            XA, nullptr, nullptr, nullptr, nullptr, WT0,
            bq, bk, bv, Qb, Kb, Vb, nullptr);

        attn_k<<<dim3(32, 4), 256, 0, stream>>>(Qb, Kb, Vb, Ob);

        mgemm_k<0, 0, 0><<<dim3(4, 8, 2), 256, 0, stream>>>(
            Ob, WT0 + 3 * D_ * D_, nullptr, PartA, nullptr, T_, D_, D_, D_ / 2);

        // LN1(X0 + wo + bo) fused into W1; writes XB
        w1ln_k<<<dim3(32, 8), 256, 0, stream>>>(
            XA, PartA, bo, ln1s, ln1b, W1T0, b1, Ffb, XB);

        mgemm_k<0, 0, 0><<<dim3(4, 8, 2), 256, 0, stream>>>(
            Ffb, W2T0, nullptr, PartA, nullptr, T_, D_, FF_, FF_ / 2);
    }

    // ---- Layer 1 ----
    {
        const ushort_t* WT1  = WT  + 4 * D_ * D_;
        const ushort_t* W1T1 = W1T + D_ * FF_;
        const ushort_t* W2T1 = W2T + FF_ * D_;

        // LN2(XB + w2 + b2) of layer 0 fused into QKV; writes XA
        qkvln_k<2><<<dim3(4, 8, 3), 256, 0, stream>>>(
            XB, PartA, b2, ln2s, ln2b, WT1,
            bq + D_, bk + D_, bv + D_, Qb, Kb, Vb, XA);

        attn_k<<<dim3(32, 4), 256, 0, stream>>>(Qb, Kb, Vb, Ob);

        mgemm_k<0, 0, 0><<<dim3(4, 8, 2), 256, 0, stream>>>(
            Ob, WT1 + 3 * D_ * D_, nullptr, PartA, nullptr, T_, D_, D_, D_ / 2);

        w1ln_k<<<dim3(32, 8), 256, 0, stream>>>(
            XA, PartA, bo + D_, ln1s + D_, ln1b + D_, W1T1, b1 + FF_, Ffb, XB);

        mgemm_k<0, 0, 0><<<dim3(4, 8, 2), 256, 0, stream>>>(
            Ffb, W2T1, nullptr, PartA, nullptr, T_, D_, FF_, FF_ / 2);
    }

    // logits with fused LN2 of layer 1
    logitsln_k<<<dim3(8, 8), 256, 0, stream>>>(
        XB, PartA, b2 + D_, ln2s + D_, ln2b + D_, embB, Lg);

    bcast_k<<<T_ * 4, 256, 0, stream>>>(Lg, temp, out);
}

// Round 10
// 177.956 us; speedup vs baseline: 1.1311x; 1.1002x over previous
//
#include <hip/hip_runtime.h>
#include <math.h>

// Problem constants (SemanticAwareTransitions_9826885173968)
#define V_  512
#define D_  256
#define H_  8
#define DH_ 32
#define FF_ 2048
#define L_  2
#define B_  4
#define S_  128
#define T_  (B_*S_)   // 512 tokens

typedef float f32x4 __attribute__((ext_vector_type(4)));
typedef short s16x8 __attribute__((ext_vector_type(8)));
typedef unsigned short u16x4 __attribute__((ext_vector_type(4)));
typedef unsigned short ushort_t;

// fp32 -> bf16 bits, round-to-nearest-even
__device__ __forceinline__ ushort_t f2b(float f) {
    unsigned int u = __builtin_bit_cast(unsigned int, f);
    u += 0x7FFFu + ((u >> 16) & 1u);
    return (ushort_t)(u >> 16);
}
__device__ __forceinline__ float b2f(ushort_t h) {
    unsigned int u = ((unsigned int)h) << 16;
    return __builtin_bit_cast(float, u);
}

__device__ __forceinline__ float waveReduceSum(float v) {
#pragma unroll
    for (int off = 32; off > 0; off >>= 1) v += __shfl_xor(v, off);
    return v;
}
__device__ __forceinline__ float waveReduceMax(float v) {
#pragma unroll
    for (int off = 32; off > 0; off >>= 1) v = fmaxf(v, __shfl_xor(v, off));
    return v;
}

// ---------------------------------------------------------------------------
// bf16 MFMA GEMM (64x64 tile, BK=64, 4 waves), double-buffered 1-barrier
// pipeline (round-6 proven). The asm barrier waits lgkmcnt only -- next
// tile's global loads stay in flight across it; ds_write auto-waits vmcnt.
// mfma_f32_16x16x32_bf16 D-layout: col=lane&15, row=(lane>>4)*4+reg.
// ---------------------------------------------------------------------------
template<int RELU, int OUTB, int BIAS>
__device__ __forceinline__ void mgemm_body(
    const ushort_t* __restrict__ A, const ushort_t* __restrict__ BT,
    const float* __restrict__ bias, float* __restrict__ Cf,
    ushort_t* __restrict__ Cb, int M, int N, int K, int kBegin, int kSteps)
{
    __shared__ ushort_t Al[2][64][72];
    __shared__ ushort_t Bl[2][64][72];
    const int tid  = threadIdx.x;
    const int m0   = blockIdx.y * 64, n0 = blockIdx.x * 64;
    const int lane = tid & 63, w = tid >> 6;
    const int srow = tid >> 2, sseg = (tid & 3) * 16;
    const int l15  = lane & 15,  kg = (lane >> 4) * 8;

    f32x4 acc0 = {0.f,0.f,0.f,0.f}, acc1 = acc0, acc2 = acc0, acc3 = acc0;

    const ushort_t* Aptr = &A [(size_t)(m0 + srow) * K + kBegin + sseg];
    const ushort_t* Bptr = &BT[(size_t)(n0 + srow) * K + kBegin + sseg];

    s16x8 av0 = *(const s16x8*)Aptr,       av1 = *(const s16x8*)(Aptr + 8);
    s16x8 bv0 = *(const s16x8*)Bptr,       bv1 = *(const s16x8*)(Bptr + 8);
    *(s16x8*)&Al[0][srow][sseg]     = av0;
    *(s16x8*)&Al[0][srow][sseg + 8] = av1;
    *(s16x8*)&Bl[0][srow][sseg]     = bv0;
    *(s16x8*)&Bl[0][srow][sseg + 8] = bv1;

    for (int kt = 0; kt < kSteps; ++kt) {
        const int cur = kt & 1;
        const bool more = (kt + 1 < kSteps);
        if (more) {                      // issue next tile's loads (in flight)
            const size_t o = (size_t)(kt + 1) * 64;
            av0 = *(const s16x8*)(Aptr + o);     av1 = *(const s16x8*)(Aptr + o + 8);
            bv0 = *(const s16x8*)(Bptr + o);     bv1 = *(const s16x8*)(Bptr + o + 8);
        }
        asm volatile("s_waitcnt lgkmcnt(0)\n\ts_barrier" ::: "memory");

        s16x8 b0  = *(const s16x8*)&Bl[cur][w * 16 + l15][kg];
        s16x8 b1  = *(const s16x8*)&Bl[cur][w * 16 + l15][kg + 32];
        s16x8 a00 = *(const s16x8*)&Al[cur][     l15][kg];
        s16x8 a01 = *(const s16x8*)&Al[cur][     l15][kg + 32];
        s16x8 a10 = *(const s16x8*)&Al[cur][16 + l15][kg];
        s16x8 a11 = *(const s16x8*)&Al[cur][16 + l15][kg + 32];
        s16x8 a20 = *(const s16x8*)&Al[cur][32 + l15][kg];
        s16x8 a21 = *(const s16x8*)&Al[cur][32 + l15][kg + 32];
        s16x8 a30 = *(const s16x8*)&Al[cur][48 + l15][kg];
        s16x8 a31 = *(const s16x8*)&Al[cur][48 + l15][kg + 32];
        acc0 = __builtin_amdgcn_mfma_f32_16x16x32_bf16(a00, b0, acc0, 0, 0, 0);
        acc1 = __builtin_amdgcn_mfma_f32_16x16x32_bf16(a10, b0, acc1, 0, 0, 0);
        acc2 = __builtin_amdgcn_mfma_f32_16x16x32_bf16(a20, b0, acc2, 0, 0, 0);
        acc3 = __builtin_amdgcn_mfma_f32_16x16x32_bf16(a30, b0, acc3, 0, 0, 0);
        acc0 = __builtin_amdgcn_mfma_f32_16x16x32_bf16(a01, b1, acc0, 0, 0, 0);
        acc1 = __builtin_amdgcn_mfma_f32_16x16x32_bf16(a11, b1, acc1, 0, 0, 0);
        acc2 = __builtin_amdgcn_mfma_f32_16x16x32_bf16(a21, b1, acc2, 0, 0, 0);
        acc3 = __builtin_amdgcn_mfma_f32_16x16x32_bf16(a31, b1, acc3, 0, 0, 0);

        if (more) {                      // auto vmcnt-wait on av/bv here
            *(s16x8*)&Al[cur ^ 1][srow][sseg]     = av0;
            *(s16x8*)&Al[cur ^ 1][srow][sseg + 8] = av1;
            *(s16x8*)&Bl[cur ^ 1][srow][sseg]     = bv0;
            *(s16x8*)&Bl[cur ^ 1][srow][sseg + 8] = bv1;
        }
    }

    const int col = n0 + w * 16 + l15;
    const float bb = BIAS ? bias[col] : 0.f;
    f32x4 accs[4] = {acc0, acc1, acc2, acc3};
#pragma unroll
    for (int r = 0; r < 4; ++r) {
#pragma unroll
        for (int e = 0; e < 4; ++e) {
            const int row = m0 + r * 16 + (lane >> 4) * 4 + e;
            float v = accs[r][e] + bb;
            if (RELU) v = fmaxf(v, 0.f);
            if (OUTB) Cb[(size_t)row * N + col] = f2b(v);
            else      Cf[(size_t)row * N + col] = v;
        }
    }
}

// Split-K: z<2 writes Cf0 + z*M*N ; z>=2 writes Cf1 + (z-2)*M*N (fp32).
template<int RELU, int OUTB, int BIAS>
__global__ __launch_bounds__(256) void mgemm_k(const ushort_t* A, const ushort_t* BT,
    const float* bias, float* Cf0, float* Cf1, ushort_t* Cb,
    int M, int N, int K, int kChunk)
{
    const int z = blockIdx.z;
    float* Cfz = nullptr;
    if (Cf0) Cfz = (z < 2) ? Cf0 + (size_t)z * M * N
                           : Cf1 + (size_t)(z - 2) * M * N;
    mgemm_body<RELU, OUTB, BIAS>(A, BT, bias, Cfz, Cb, M, N, K,
                                 z * kChunk, kChunk / 64);
}

// ---------------------------------------------------------------------------
// Fused QKV projection + attention. Grid (32 bh, 4 quarters) = 128 blocks,
// 256 thr = 4 waves -- SAME parallelism as the round-6 attn kernel.
// Projection: register-streaming MFMA straight from L2 (no LDS staging, no
// barriers; K/V share A-frags). Each block computes its quarter's Q (32x32)
// and the full K/V head tiles (128x32, 4x redundant -- trivial MFLOP).
// Q/K/V stay fp32 in LDS (no bf16 round-trip). Then round-6 attention body.
// Wave roles: wave w -> K/V rows 32w..32w+31 (2 Mfrag x 2 Nfrag); Q unit
// (Mfrag=w>>1, Nfrag=w&1). MFMA D: col=lane&15(dh), row=(lane>>4)*4+e(token).
// ---------------------------------------------------------------------------
__global__ __launch_bounds__(256) void qkvattn_k(
    const ushort_t* __restrict__ Xb, const ushort_t* __restrict__ WT,
    const float* __restrict__ bq, const float* __restrict__ bk,
    const float* __restrict__ bv, ushort_t* __restrict__ Ob)
{
    __shared__ float Qs[32][36], Ks[128][36], Vs[128][36], Ps[32][132];
    const int bh = blockIdx.x, b = bh >> 3, h = bh & 7;
    const int i0 = blockIdx.y * 32;
    const int tid = threadIdx.x;
    const int w = tid >> 6, lane = tid & 63;
    const int l15 = lane & 15, kg = (lane >> 4) * 8;

    {   // ---- QKV projection ----
        const ushort_t* WqT = WT + (size_t)(h * DH_) * D_;           // [n][k]
        const ushort_t* WkT = WqT + (size_t)D_ * D_;
        const ushort_t* WvT = WqT + 2 * (size_t)D_ * D_;
        const ushort_t* Akv = Xb + (size_t)(b * S_ + w * 32) * D_;   // K/V rows
        const int qmf = w >> 1, qnf = w & 1;
        const ushort_t* Aq  = Xb + (size_t)(b * S_ + i0 + qmf * 16) * D_;

        f32x4 kacc00 = {0.f,0.f,0.f,0.f}, kacc01 = kacc00, kacc10 = kacc00, kacc11 = kacc00;
        f32x4 vacc00 = kacc00, vacc01 = kacc00, vacc10 = kacc00, vacc11 = kacc00;
        f32x4 qacc = kacc00;
#pragma unroll
        for (int kk = 0; kk < 8; ++kk) {
            const int k0 = kk * 32 + kg;
            s16x8 a0  = *(const s16x8*)&Akv[(size_t)(     l15) * D_ + k0];
            s16x8 a1  = *(const s16x8*)&Akv[(size_t)(16 + l15) * D_ + k0];
            s16x8 aq  = *(const s16x8*)&Aq [(size_t)(     l15) * D_ + k0];
            s16x8 wk0 = *(const s16x8*)&WkT[(size_t)(     l15) * D_ + k0];
            s16x8 wk1 = *(const s16x8*)&WkT[(size_t)(16 + l15) * D_ + k0];
            s16x8 wv0 = *(const s16x8*)&WvT[(size_t)(     l15) * D_ + k0];
            s16x8 wv1 = *(const s16x8*)&WvT[(size_t)(16 + l15) * D_ + k0];
            s16x8 wq  = *(const s16x8*)&WqT[(size_t)(qnf * 16 + l15) * D_ + k0];
            kacc00 = __builtin_amdgcn_mfma_f32_16x16x32_bf16(a0, wk0, kacc00, 0, 0, 0);
            kacc01 = __builtin_amdgcn_mfma_f32_16x16x32_bf16(a0, wk1, kacc01, 0, 0, 0);
            kacc10 = __builtin_amdgcn_mfma_f32_16x16x32_bf16(a1, wk0, kacc10, 0, 0, 0);
            kacc11 = __builtin_amdgcn_mfma_f32_16x16x32_bf16(a1, wk1, kacc11, 0, 0, 0);
            vacc00 = __builtin_amdgcn_mfma_f32_16x16x32_bf16(a0, wv0, vacc00, 0, 0, 0);
            vacc01 = __builtin_amdgcn_mfma_f32_16x16x32_bf16(a0, wv1, vacc01, 0, 0, 0);
            vacc10 = __builtin_amdgcn_mfma_f32_16x16x32_bf16(a1, wv0, vacc10, 0, 0, 0);
            vacc11 = __builtin_amdgcn_mfma_f32_16x16x32_bf16(a1, wv1, vacc11, 0, 0, 0);
            qacc   = __builtin_amdgcn_mfma_f32_16x16x32_bf16(aq, wq,  qacc,   0, 0, 0);
        }
        const int r0 = (lane >> 4) * 4;
        f32x4 kaccs[2][2] = {{kacc00, kacc01}, {kacc10, kacc11}};
        f32x4 vaccs[2][2] = {{vacc00, vacc01}, {vacc10, vacc11}};
#pragma unroll
        for (int mf = 0; mf < 2; ++mf) {
#pragma unroll
            for (int nf = 0; nf < 2; ++nf) {
                const int col = nf * 16 + l15;
                const float kb = bk[h * DH_ + col];
                const float vb = bv[h * DH_ + col];
#pragma unroll
                for (int e = 0; e < 4; ++e) {
                    Ks[w * 32 + mf * 16 + r0 + e][col] = kaccs[mf][nf][e] + kb;
                    Vs[w * 32 + mf * 16 + r0 + e][col] = vaccs[mf][nf][e] + vb;
                }
            }
        }
        {
            const int col = qnf * 16 + l15;
            const float qb = bq[h * DH_ + col];
#pragma unroll
            for (int e = 0; e < 4; ++e)
                Qs[qmf * 16 + r0 + e][col] = qacc[e] + qb;
        }
    }
    __syncthreads();

    // ---- attention (round-6 proven body) ----
    const int i = tid >> 3, jg = tid & 7;
    const float sc = 0.17677669529663687f;   // 1/sqrt(32)
    float sv[16];
    float mx = -1e30f;
#pragma unroll
    for (int jj = 0; jj < 16; ++jj) {
        const int j = jg + jj * 8;
        f32x4 a4 = {0.f,0.f,0.f,0.f};
#pragma unroll
        for (int kk = 0; kk < 8; ++kk) {
            f32x4 q = *(const f32x4*)&Qs[i][kk * 4];
            f32x4 k = *(const f32x4*)&Ks[j][kk * 4];
            a4 += q * k;
        }
        const float sdot = (a4[0] + a4[1] + a4[2] + a4[3]) * sc;
        sv[jj] = sdot;
        mx = fmaxf(mx, sdot);
    }
    mx = fmaxf(mx, __shfl_xor(mx, 1));
    mx = fmaxf(mx, __shfl_xor(mx, 2));
    mx = fmaxf(mx, __shfl_xor(mx, 4));
    float sum = 0.f;
#pragma unroll
    for (int jj = 0; jj < 16; ++jj) {
        const float e = __expf(sv[jj] - mx);
        Ps[i][jg + jj * 8] = e;
        sum += e;
    }
    sum += __shfl_xor(sum, 1);
    sum += __shfl_xor(sum, 2);
    sum += __shfl_xor(sum, 4);
    const float inv = 1.f / sum;
    __syncthreads();

    const int dg = tid & 7;
    f32x4 o = {0.f,0.f,0.f,0.f};
#pragma unroll 4
    for (int j = 0; j < 128; ++j) {
        const float p = Ps[i][j];
        f32x4 vv = *(const f32x4*)&Vs[j][dg * 4];
        o += vv * p;
    }
    u16x4 ov;
    ov[0] = f2b(o[0] * inv); ov[1] = f2b(o[1] * inv);
    ov[2] = f2b(o[2] * inv); ov[3] = f2b(o[3] * inv);
    *(u16x4*)&Ob[(size_t)(b * S_ + i0 + i) * D_ + h * DH_ + dg * 4] = ov;
}

// ---------------------------------------------------------------------------
// prep: blocks [0,512) = embedding gather (+bf16 X and emb); [512,3072) =
// weight transpose fp32 [R][C] -> bf16 [C][R] in 32x32 LDS tiles.
// ---------------------------------------------------------------------------
__global__ __launch_bounds__(256) void prep_k(const int* __restrict__ xt,
    const float* __restrict__ emb, float* __restrict__ X,
    ushort_t* __restrict__ Xb, ushort_t* __restrict__ embB,
    const float* __restrict__ Wq, const float* __restrict__ Wk,
    const float* __restrict__ Wv, const float* __restrict__ Wo,
    const float* __restrict__ W1, const float* __restrict__ W2,
    ushort_t* __restrict__ WT, ushort_t* __restrict__ W1T, ushort_t* __restrict__ W2T)
{
    __shared__ float Tl[32][33];
    const int tid = threadIdx.x;
    if (blockIdx.x < 512) {
        const int idx = blockIdx.x * 256 + tid;       // < T_*D_ == V_*D_
        const int t = idx >> 8, d = idx & 255;
        const float v = emb[(size_t)xt[t] * D_ + d];
        X[idx]  = v;
        Xb[idx] = f2b(v);
        embB[idx] = f2b(emb[idx]);
        return;
    }
    const int id = blockIdx.x - 512;
    const int l  = id >= 1280 ? 1 : 0;
    const int t  = id - l * 1280;
    const float* src; ushort_t* dst; int R, C, rt, ct;
    if (t < 256) {
        const int kind = t >> 6, tl = t & 63;
        const float* s0 = (kind == 0) ? Wq : (kind == 1) ? Wk : (kind == 2) ? Wv : Wo;
        src = s0 + (size_t)l * (D_ * D_);
        dst = WT + (size_t)l * (4 * D_ * D_) + (size_t)kind * (D_ * D_);
        R = D_; C = D_; rt = tl >> 3; ct = tl & 7;
    } else if (t < 768) {
        const int tl = t - 256;
        src = W1 + (size_t)l * (D_ * FF_); dst = W1T + (size_t)l * (D_ * FF_);
        R = D_; C = FF_; rt = tl >> 6; ct = tl & 63;
    } else {
        const int tl = t - 768;
        src = W2 + (size_t)l * (FF_ * D_); dst = W2T + (size_t)l * (FF_ * D_);
        R = FF_; C = D_; rt = tl >> 3; ct = tl & 7;
    }
    const int r = tid >> 3, c4 = (tid & 7) * 4;
    f32x4 v = *(const f32x4*)&src[(size_t)(rt * 32 + r) * C + ct * 32 + c4];
    Tl[r][c4] = v[0]; Tl[r][c4 + 1] = v[1]; Tl[r][c4 + 2] = v[2]; Tl[r][c4 + 3] = v[3];
    __syncthreads();
    u16x4 ov;
    ov[0] = f2b(Tl[c4 + 0][r]); ov[1] = f2b(Tl[c4 + 1][r]);
    ov[2] = f2b(Tl[c4 + 2][r]); ov[3] = f2b(Tl[c4 + 3][r]);
    *(u16x4*)&dst[(size_t)(ct * 32 + r) * R + rt * 32 + c4] = ov;
}

// ---------------------------------------------------------------------------
// x = LN(x + sum parts + bias) * s + b ; writes fp32 X and bf16 Xb.
// nparts in {2,4}: parts 0-1 live in p0[0],p0[TD]; parts 2-3 in p1.
// ---------------------------------------------------------------------------
__global__ __launch_bounds__(256) void add_ln_k(
    const float* __restrict__ p0, const float* __restrict__ p1, int nparts,
    const float* __restrict__ bias, float* __restrict__ X,
    ushort_t* __restrict__ Xb, const float* __restrict__ s,
    const float* __restrict__ b)
{
    __shared__ float red[4];
    const int row = blockIdx.x, tid = threadIdx.x;
    const size_t off = (size_t)row * D_ + tid;
    const size_t TD = (size_t)T_ * D_;
    float a = X[off] + bias[tid] + p0[off];
    if (nparts >= 2) a += p0[TD + off];
    if (nparts == 4) a += p1[off] + p1[TD + off];

    float ws_ = waveReduceSum(a);
    if ((tid & 63) == 0) red[tid >> 6] = ws_;
    __syncthreads();
    const float mean = (red[0] + red[1] + red[2] + red[3]) * (1.f / D_);
    __syncthreads();
    const float d = a - mean;
    float vs = waveReduceSum(d * d);
    if ((tid & 63) == 0) red[tid >> 6] = vs;
    __syncthreads();
    const float var = (red[0] + red[1] + red[2] + red[3]) * (1.f / D_);
    const float y = d * rsqrtf(var + 1e-5f) * s[tid] + b[tid];
    X[off]  = y;
    Xb[off] = f2b(y);
}

// ---------------------------------------------------------------------------
// Fused final softmax + broadcast: block = (token t, quarter of row-range).
// Each block re-computes softmax(t) (cheap, 4x redundant) then streams 128
// rows of 2KB with nontemporal float4 stores.
// ---------------------------------------------------------------------------
__global__ __launch_bounds__(256) void bcast_k(const float* __restrict__ Lg,
    const float* __restrict__ temp, float* __restrict__ out)
{
    __shared__ float row[V_];
    __shared__ float red[4];
    const int blk = blockIdx.x, t = blk >> 2, quarter = blk & 3;
    const int tid = threadIdx.x;
    const float rT = 1.f / temp[0];
    const float l0 = Lg[(size_t)t * V_ + tid] * rT;
    const float l1 = Lg[(size_t)t * V_ + 256 + tid] * rT;
    float m = waveReduceMax(fmaxf(l0, l1));
    if ((tid & 63) == 0) red[tid >> 6] = m;
    __syncthreads();
    m = fmaxf(fmaxf(red[0], red[1]), fmaxf(red[2], red[3]));
    __syncthreads();
    const float e0 = __expf(l0 - m), e1 = __expf(l1 - m);
    float sblk = waveReduceSum(e0 + e1);
    if ((tid & 63) == 0) red[tid >> 6] = sblk;
    __syncthreads();
    const float inv = 1.f / (red[0] + red[1] + red[2] + red[3]);
    row[tid] = e0 * inv;
    row[tid + 256] = e1 * inv;
    __syncthreads();

    const int c = tid & 127, ihalf = tid >> 7;
    f32x4 v = *(const f32x4*)&row[c * 4];
    f32x4* dst = (f32x4*)out + (size_t)t * V_ * (V_ / 4);
#pragma unroll 4
    for (int r = 0; r < 64; ++r) {
        const int i = quarter * 128 + ihalf + r * 2;
        __builtin_nontemporal_store(v, &dst[(size_t)i * (V_ / 4) + c]);
    }
}

// ---------------------------------------------------------------------------
// Host launch. ws layout (bytes), total 10.0 MB (round-6 layout):
//   0        X     fp32 512KB
//   524288   PartA fp32 2x512KB (split-K parts 0-1; alias Lg at end)
//   1572864  PartB fp32 2x512KB (W2 split-K parts 2-3)
//   2359296  Ob    bf16 256KB   (inside PartB range; disjoint lifetime --
//                                Ob is consumed by Wo before W2 runs)
//   2621440  Xb    bf16 256KB
//   2883584  Ffb   bf16 2MB
//   4980736  embB  bf16 256KB
//   5242880  WT    bf16 1MB
//   6291456  W1T   bf16 2MB
//   8388608  W2T   bf16 2MB   -> end 10485760
// ---------------------------------------------------------------------------
extern "C" void kernel_launch(void* const* d_in, const int* in_sizes, int n_in,
                              void* d_out, int out_size, void* d_ws, size_t ws_size,
                              hipStream_t stream)
{
    const int*   x_t  = (const int*)  d_in[0];
    const float* emb  = (const float*)d_in[1];
    const float* temp = (const float*)d_in[2];
    const float* Wq   = (const float*)d_in[3];
    const float* Wk   = (const float*)d_in[4];
    const float* Wv   = (const float*)d_in[5];
    const float* Wo   = (const float*)d_in[6];
    const float* bq   = (const float*)d_in[7];
    const float* bk   = (const float*)d_in[8];
    const float* bv   = (const float*)d_in[9];
    const float* bo   = (const float*)d_in[10];
    const float* W1   = (const float*)d_in[11];
    const float* b1   = (const float*)d_in[12];
    const float* W2   = (const float*)d_in[13];
    const float* b2   = (const float*)d_in[14];
    const float* ln1s = (const float*)d_in[15];
    const float* ln1b = (const float*)d_in[16];
    const float* ln2s = (const float*)d_in[17];
    const float* ln2b = (const float*)d_in[18];

    float* out = (float*)d_out;
    char*  wsb = (char*)d_ws;

    float*    X     = (float*)   (wsb + 0);
    float*    PartA = (float*)   (wsb + 524288);
    float*    Lg    = PartA;                        // alias (disjoint lifetime)
    float*    PartB = (float*)   (wsb + 1572864);
    ushort_t* Ob    = (ushort_t*)(wsb + 2359296);
    ushort_t* Xb    = (ushort_t*)(wsb + 2621440);
    ushort_t* Ffb   = (ushort_t*)(wsb + 2883584);
    ushort_t* embB  = (ushort_t*)(wsb + 4980736);
    ushort_t* WT    = (ushort_t*)(wsb + 5242880);
    ushort_t* W1T   = (ushort_t*)(wsb + 6291456);
    ushort_t* W2T   = (ushort_t*)(wsb + 8388608);

    prep_k<<<3072, 256, 0, stream>>>(x_t, emb, X, Xb, embB,
                                     Wq, Wk, Wv, Wo, W1, W2, WT, W1T, W2T);

    for (int l = 0; l < L_; ++l) {
        const ushort_t* WTl  = WT  + (size_t)l * (4 * D_ * D_);
        const ushort_t* W1Tl = W1T + (size_t)l * (D_ * FF_);
        const ushort_t* W2Tl = W2T + (size_t)l * (FF_ * D_);

        // QKV projection fused into attention: 128 blocks (b,h,quarter)
        qkvattn_k<<<dim3(32, 4), 256, 0, stream>>>(
            Xb, WTl, bq + l * D_, bk + l * D_, bv + l * D_, Ob);

        // o @ Wo split-K z=2 -> PartA[0..1]; bias bo folded into add_ln
        mgemm_k<0, 0, 0><<<dim3(4, 8, 2), 256, 0, stream>>>(
            Ob, WTl + 3 * D_ * D_, nullptr, PartA, nullptr, nullptr,
            T_, D_, D_, D_ / 2);
        add_ln_k<<<T_, 256, 0, stream>>>(PartA, nullptr, 2, bo + l * D_,
                                         X, Xb, ln1s + l * D_, ln1b + l * D_);

        // relu(x @ W1 + b1) -> Ffb (bf16)
        mgemm_k<1, 1, 1><<<dim3(32, 8, 1), 256, 0, stream>>>(
            Xb, W1Tl, b1 + l * FF_, nullptr, nullptr, Ffb, T_, FF_, D_, D_);

        // Ffb @ W2 split-K z=4 -> PartA[0..1] + PartB[0..1]; b2 in add_ln
        mgemm_k<0, 0, 0><<<dim3(4, 8, 4), 256, 0, stream>>>(
            Ffb, W2Tl, nullptr, PartA, PartB, nullptr, T_, D_, FF_, FF_ / 4);
        add_ln_k<<<T_, 256, 0, stream>>>(PartA, PartB, 4, b2 + l * D_,
                                         X, Xb, ln2s + l * D_, ln2b + l * D_);
    }

    // logits = Xb @ embB^T -> Lg (fp32)
    mgemm_k<0, 0, 0><<<dim3(8, 8, 1), 256, 0, stream>>>(
        Xb, embB, nullptr, Lg, nullptr, nullptr, T_, V_, D_, D_);

    bcast_k<<<T_ * 4, 256, 0, stream>>>(Lg, temp, out);
}

// Round 11
// 173.045 us; speedup vs baseline: 1.1632x; 1.0284x over previous
//
#include <hip/hip_runtime.h>
#include <math.h>

// Problem constants (SemanticAwareTransitions_9826885173968)
#define V_  512
#define D_  256
#define H_  8
#define DH_ 32
#define FF_ 2048
#define L_  2
#define B_  4
#define S_  128
#define T_  (B_*S_)   // 512 tokens

typedef float f32x4 __attribute__((ext_vector_type(4)));
typedef short s16x8 __attribute__((ext_vector_type(8)));
typedef unsigned short u16x4 __attribute__((ext_vector_type(4)));
typedef unsigned short ushort_t;

// fp32 -> bf16 bits, round-to-nearest-even
__device__ __forceinline__ ushort_t f2b(float f) {
    unsigned int u = __builtin_bit_cast(unsigned int, f);
    u += 0x7FFFu + ((u >> 16) & 1u);
    return (ushort_t)(u >> 16);
}
__device__ __forceinline__ float b2f(ushort_t h) {
    unsigned int u = ((unsigned int)h) << 16;
    return __builtin_bit_cast(float, u);
}

__device__ __forceinline__ float waveReduceSum(float v) {
#pragma unroll
    for (int off = 32; off > 0; off >>= 1) v += __shfl_xor(v, off);
    return v;
}
__device__ __forceinline__ float waveReduceMax(float v) {
#pragma unroll
    for (int off = 32; off > 0; off >>= 1) v = fmaxf(v, __shfl_xor(v, off));
    return v;
}

// ---------------------------------------------------------------------------
// bf16 MFMA GEMM (64x64 tile, BK=64, 4 waves), double-buffered 1-barrier
// pipeline. BK=64 halves the barrier count vs BK=32 and doubles the per-step
// MFMA phase (~160cyc/wave: 8 MFMA + 10 ds_read_b128), covering most of the
// ~200-300cyc L2 load latency with depth-1 prefetch. The asm barrier waits
// lgkmcnt only -- next tile's global loads stay in flight across it; the
// ds_write of the next buffer auto-waits vmcnt after the MFMAs.
// Row pad 72 shorts: 16-lane frag reads alias banks 2-way (free, m136).
// mfma_f32_16x16x32_bf16 D-layout: col=lane&15, row=(lane>>4)*4+reg.
// ---------------------------------------------------------------------------
template<int RELU, int OUTB, int BIAS>
__device__ __forceinline__ void mgemm_body(
    const ushort_t* __restrict__ A, const ushort_t* __restrict__ BT,
    const float* __restrict__ bias, float* __restrict__ Cf,
    ushort_t* __restrict__ Cb, int M, int N, int K, int kBegin, int kSteps)
{
    __shared__ ushort_t Al[2][64][72];
    __shared__ ushort_t Bl[2][64][72];
    const int tid  = threadIdx.x;
    const int m0   = blockIdx.y * 64, n0 = blockIdx.x * 64;
    const int lane = tid & 63, w = tid >> 6;
    const int srow = tid >> 2, sseg = (tid & 3) * 16;
    const int l15  = lane & 15,  kg = (lane >> 4) * 8;

    f32x4 acc0 = {0.f,0.f,0.f,0.f}, acc1 = acc0, acc2 = acc0, acc3 = acc0;

    const ushort_t* Aptr = &A [(size_t)(m0 + srow) * K + kBegin + sseg];
    const ushort_t* Bptr = &BT[(size_t)(n0 + srow) * K + kBegin + sseg];

    // prologue: stage tile 0 into buffer 0
    s16x8 av0 = *(const s16x8*)Aptr,       av1 = *(const s16x8*)(Aptr + 8);
    s16x8 bv0 = *(const s16x8*)Bptr,       bv1 = *(const s16x8*)(Bptr + 8);
    *(s16x8*)&Al[0][srow][sseg]     = av0;
    *(s16x8*)&Al[0][srow][sseg + 8] = av1;
    *(s16x8*)&Bl[0][srow][sseg]     = bv0;
    *(s16x8*)&Bl[0][srow][sseg + 8] = bv1;

    for (int kt = 0; kt < kSteps; ++kt) {
        const int cur = kt & 1;
        const bool more = (kt + 1 < kSteps);
        if (more) {                      // issue next tile's loads (in flight)
            const size_t o = (size_t)(kt + 1) * 64;
            av0 = *(const s16x8*)(Aptr + o);     av1 = *(const s16x8*)(Aptr + o + 8);
            bv0 = *(const s16x8*)(Bptr + o);     bv1 = *(const s16x8*)(Bptr + o + 8);
        }
        // own LDS ops drained; global loads NOT drained (complete under MFMAs)
        asm volatile("s_waitcnt lgkmcnt(0)\n\ts_barrier" ::: "memory");

        s16x8 b0 = *(const s16x8*)&Bl[cur][w * 16 + l15][kg];
        s16x8 b1 = *(const s16x8*)&Bl[cur][w * 16 + l15][kg + 32];
        s16x8 a00 = *(const s16x8*)&Al[cur][     l15][kg];
        s16x8 a01 = *(const s16x8*)&Al[cur][     l15][kg + 32];
        s16x8 a10 = *(const s16x8*)&Al[cur][16 + l15][kg];
        s16x8 a11 = *(const s16x8*)&Al[cur][16 + l15][kg + 32];
        s16x8 a20 = *(const s16x8*)&Al[cur][32 + l15][kg];
        s16x8 a21 = *(const s16x8*)&Al[cur][32 + l15][kg + 32];
        s16x8 a30 = *(const s16x8*)&Al[cur][48 + l15][kg];
        s16x8 a31 = *(const s16x8*)&Al[cur][48 + l15][kg + 32];
        acc0 = __builtin_amdgcn_mfma_f32_16x16x32_bf16(a00, b0, acc0, 0, 0, 0);
        acc1 = __builtin_amdgcn_mfma_f32_16x16x32_bf16(a10, b0, acc1, 0, 0, 0);
        acc2 = __builtin_amdgcn_mfma_f32_16x16x32_bf16(a20, b0, acc2, 0, 0, 0);
        acc3 = __builtin_amdgcn_mfma_f32_16x16x32_bf16(a30, b0, acc3, 0, 0, 0);
        acc0 = __builtin_amdgcn_mfma_f32_16x16x32_bf16(a01, b1, acc0, 0, 0, 0);
        acc1 = __builtin_amdgcn_mfma_f32_16x16x32_bf16(a11, b1, acc1, 0, 0, 0);
        acc2 = __builtin_amdgcn_mfma_f32_16x16x32_bf16(a21, b1, acc2, 0, 0, 0);
        acc3 = __builtin_amdgcn_mfma_f32_16x16x32_bf16(a31, b1, acc3, 0, 0, 0);

        if (more) {                      // auto vmcnt-wait on av/bv here
            *(s16x8*)&Al[cur ^ 1][srow][sseg]     = av0;
            *(s16x8*)&Al[cur ^ 1][srow][sseg + 8] = av1;
            *(s16x8*)&Bl[cur ^ 1][srow][sseg]     = bv0;
            *(s16x8*)&Bl[cur ^ 1][srow][sseg + 8] = bv1;
        }
    }

    const int col = n0 + w * 16 + l15;
    const float bb = BIAS ? bias[col] : 0.f;
    f32x4 accs[4] = {acc0, acc1, acc2, acc3};
#pragma unroll
    for (int r = 0; r < 4; ++r) {
#pragma unroll
        for (int e = 0; e < 4; ++e) {
            const int row = m0 + r * 16 + (lane >> 4) * 4 + e;
            float v = accs[r][e] + bb;
            if (RELU) v = fmaxf(v, 0.f);
            if (OUTB) Cb[(size_t)row * N + col] = f2b(v);
            else      Cf[(size_t)row * N + col] = v;
        }
    }
}

// Split-K: z<2 writes Cf0 + z*M*N ; z>=2 writes Cf1 + (z-2)*M*N (fp32).
template<int RELU, int OUTB, int BIAS>
__global__ __launch_bounds__(256) void mgemm_k(const ushort_t* A, const ushort_t* BT,
    const float* bias, float* Cf0, float* Cf1, ushort_t* Cb,
    int M, int N, int K, int kChunk)
{
    const int z = blockIdx.z;
    float* Cfz = nullptr;
    if (Cf0) Cfz = (z < 2) ? Cf0 + (size_t)z * M * N
                           : Cf1 + (size_t)(z - 2) * M * N;
    mgemm_body<RELU, OUTB, BIAS>(A, BT, bias, Cfz, Cb, M, N, K,
                                 z * kChunk, kChunk / 64);
}

__global__ __launch_bounds__(256) void qkv_k(const ushort_t* Xb, const ushort_t* WT,
    const float* bq, const float* bk, const float* bv,
    ushort_t* Qb, ushort_t* Kb, ushort_t* Vb)
{
    const int z = blockIdx.z;
    const ushort_t* bt = WT + (size_t)z * (D_ * D_);
    const float* bias; ushort_t* out;
    if (z == 0)      { bias = bq; out = Qb; }
    else if (z == 1) { bias = bk; out = Kb; }
    else             { bias = bv; out = Vb; }
    mgemm_body<0, 1, 1>(Xb, bt, bias, nullptr, out, T_, D_, D_, 0, D_ / 64);
}

// ---------------------------------------------------------------------------
// prep: blocks [0,512) = embedding gather (+bf16 X and emb); [512,3072) =
// weight transpose fp32 [R][C] -> bf16 [C][R] in 32x32 LDS tiles.
// ---------------------------------------------------------------------------
__global__ __launch_bounds__(256) void prep_k(const int* __restrict__ xt,
    const float* __restrict__ emb, float* __restrict__ X,
    ushort_t* __restrict__ Xb, ushort_t* __restrict__ embB,
    const float* __restrict__ Wq, const float* __restrict__ Wk,
    const float* __restrict__ Wv, const float* __restrict__ Wo,
    const float* __restrict__ W1, const float* __restrict__ W2,
    ushort_t* __restrict__ WT, ushort_t* __restrict__ W1T, ushort_t* __restrict__ W2T)
{
    __shared__ float Tl[32][33];
    const int tid = threadIdx.x;
    if (blockIdx.x < 512) {
        const int idx = blockIdx.x * 256 + tid;       // < T_*D_ == V_*D_
        const int t = idx >> 8, d = idx & 255;
        const float v = emb[(size_t)xt[t] * D_ + d];
        X[idx]  = v;
        Xb[idx] = f2b(v);
        embB[idx] = f2b(emb[idx]);
        return;
    }
    const int id = blockIdx.x - 512;
    const int l  = id >= 1280 ? 1 : 0;
    const int t  = id - l * 1280;
    const float* src; ushort_t* dst; int R, C, rt, ct;
    if (t < 256) {
        const int kind = t >> 6, tl = t & 63;
        const float* s0 = (kind == 0) ? Wq : (kind == 1) ? Wk : (kind == 2) ? Wv : Wo;
        src = s0 + (size_t)l * (D_ * D_);
        dst = WT + (size_t)l * (4 * D_ * D_) + (size_t)kind * (D_ * D_);
        R = D_; C = D_; rt = tl >> 3; ct = tl & 7;
    } else if (t < 768) {
        const int tl = t - 256;
        src = W1 + (size_t)l * (D_ * FF_); dst = W1T + (size_t)l * (D_ * FF_);
        R = D_; C = FF_; rt = tl >> 6; ct = tl & 63;
    } else {
        const int tl = t - 768;
        src = W2 + (size_t)l * (FF_ * D_); dst = W2T + (size_t)l * (FF_ * D_);
        R = FF_; C = D_; rt = tl >> 3; ct = tl & 7;
    }
    const int r = tid >> 3, c4 = (tid & 7) * 4;
    f32x4 v = *(const f32x4*)&src[(size_t)(rt * 32 + r) * C + ct * 32 + c4];
    Tl[r][c4] = v[0]; Tl[r][c4 + 1] = v[1]; Tl[r][c4 + 2] = v[2]; Tl[r][c4 + 3] = v[3];
    __syncthreads();
    u16x4 ov;
    ov[0] = f2b(Tl[c4 + 0][r]); ov[1] = f2b(Tl[c4 + 1][r]);
    ov[2] = f2b(Tl[c4 + 2][r]); ov[3] = f2b(Tl[c4 + 3][r]);
    *(u16x4*)&dst[(size_t)(ct * 32 + r) * R + rt * 32 + c4] = ov;
}

// ---------------------------------------------------------------------------
// x = LN(x + sum parts + bias) * s + b ; writes fp32 X and bf16 Xb.
// nparts in {1,2,4}: parts 0-1 live in p0[0],p0[TD]; parts 2-3 in p1.
// ---------------------------------------------------------------------------
__global__ __launch_bounds__(256) void add_ln_k(
    const float* __restrict__ p0, const float* __restrict__ p1, int nparts,
    const float* __restrict__ bias, float* __restrict__ X,
    ushort_t* __restrict__ Xb, const float* __restrict__ s,
    const float* __restrict__ b)
{
    __shared__ float red[4];
    const int row = blockIdx.x, tid = threadIdx.x;
    const size_t off = (size_t)row * D_ + tid;
    const size_t TD = (size_t)T_ * D_;
    float a = X[off] + bias[tid] + p0[off];
    if (nparts >= 2) a += p0[TD + off];
    if (nparts == 4) a += p1[off] + p1[TD + off];

    float ws_ = waveReduceSum(a);
    if ((tid & 63) == 0) red[tid >> 6] = ws_;
    __syncthreads();
    const float mean = (red[0] + red[1] + red[2] + red[3]) * (1.f / D_);
    __syncthreads();
    const float d = a - mean;
    float vs = waveReduceSum(d * d);
    if ((tid & 63) == 0) red[tid >> 6] = vs;
    __syncthreads();
    const float var = (red[0] + red[1] + red[2] + red[3]) * (1.f / D_);
    const float y = d * rsqrtf(var + 1e-5f) * s[tid] + b[tid];
    X[off]  = y;
    Xb[off] = f2b(y);
}

// ---------------------------------------------------------------------------
// Fused attention: one block per (b,h,q-quarter). fp32 math, bf16 I/O.
// ---------------------------------------------------------------------------
__global__ __launch_bounds__(256) void attn_k(const ushort_t* __restrict__ Qb,
    const ushort_t* __restrict__ Kb, const ushort_t* __restrict__ Vb,
    ushort_t* __restrict__ Ob)
{
    __shared__ float Qs[32][36], Ks[128][36], Vs[128][36], Ps[32][132];
    const int bh = blockIdx.x, b = bh >> 3, h = bh & 7;
    const int i0 = blockIdx.y * 32;
    const int tid = threadIdx.x;

#pragma unroll
    for (int it = 0; it < 2; ++it) {                 // K,V: 512 8-elem chunks
        const int g = it * 256 + tid;
        const int r = g >> 2, c8 = (g & 3) * 8;
        s16x8 kv = *(const s16x8*)&Kb[(size_t)(b * S_ + r) * D_ + h * DH_ + c8];
        s16x8 vv = *(const s16x8*)&Vb[(size_t)(b * S_ + r) * D_ + h * DH_ + c8];
        f32x4 klo = {b2f((ushort_t)kv[0]), b2f((ushort_t)kv[1]), b2f((ushort_t)kv[2]), b2f((ushort_t)kv[3])};
        f32x4 khi = {b2f((ushort_t)kv[4]), b2f((ushort_t)kv[5]), b2f((ushort_t)kv[6]), b2f((ushort_t)kv[7])};
        f32x4 vlo = {b2f((ushort_t)vv[0]), b2f((ushort_t)vv[1]), b2f((ushort_t)vv[2]), b2f((ushort_t)vv[3])};
        f32x4 vhi = {b2f((ushort_t)vv[4]), b2f((ushort_t)vv[5]), b2f((ushort_t)vv[6]), b2f((ushort_t)vv[7])};
        *(f32x4*)&Ks[r][c8]     = klo;  *(f32x4*)&Ks[r][c8 + 4] = khi;
        *(f32x4*)&Vs[r][c8]     = vlo;  *(f32x4*)&Vs[r][c8 + 4] = vhi;
    }
    if (tid < 128) {                                  // Q: 128 chunks
        const int r = tid >> 2, c8 = (tid & 3) * 8;
        s16x8 qv = *(const s16x8*)&Qb[(size_t)(b * S_ + i0 + r) * D_ + h * DH_ + c8];
        f32x4 qlo = {b2f((ushort_t)qv[0]), b2f((ushort_t)qv[1]), b2f((ushort_t)qv[2]), b2f((ushort_t)qv[3])};
        f32x4 qhi = {b2f((ushort_t)qv[4]), b2f((ushort_t)qv[5]), b2f((ushort_t)qv[6]), b2f((ushort_t)qv[7])};
        *(f32x4*)&Qs[r][c8] = qlo;  *(f32x4*)&Qs[r][c8 + 4] = qhi;
    }
    __syncthreads();

    const int i = tid >> 3, jg = tid & 7;
    const float sc = 0.17677669529663687f;   // 1/sqrt(32)
    float sv[16];
    float mx = -1e30f;
#pragma unroll
    for (int jj = 0; jj < 16; ++jj) {
        const int j = jg + jj * 8;
        f32x4 a4 = {0.f,0.f,0.f,0.f};
#pragma unroll
        for (int kk = 0; kk < 8; ++kk) {
            f32x4 q = *(const f32x4*)&Qs[i][kk * 4];
            f32x4 k = *(const f32x4*)&Ks[j][kk * 4];
            a4 += q * k;
        }
        const float sdot = (a4[0] + a4[1] + a4[2] + a4[3]) * sc;
        sv[jj] = sdot;
        mx = fmaxf(mx, sdot);
    }
    mx = fmaxf(mx, __shfl_xor(mx, 1));
    mx = fmaxf(mx, __shfl_xor(mx, 2));
    mx = fmaxf(mx, __shfl_xor(mx, 4));
    float sum = 0.f;
#pragma unroll
    for (int jj = 0; jj < 16; ++jj) {
        const float e = __expf(sv[jj] - mx);
        Ps[i][jg + jj * 8] = e;
        sum += e;
    }
    sum += __shfl_xor(sum, 1);
    sum += __shfl_xor(sum, 2);
    sum += __shfl_xor(sum, 4);
    const float inv = 1.f / sum;
    __syncthreads();

    const int dg = tid & 7;
    f32x4 o = {0.f,0.f,0.f,0.f};
#pragma unroll 4
    for (int j = 0; j < 128; ++j) {
        const float p = Ps[i][j];
        f32x4 vv = *(const f32x4*)&Vs[j][dg * 4];
        o += vv * p;
    }
    u16x4 ov;
    ov[0] = f2b(o[0] * inv); ov[1] = f2b(o[1] * inv);
    ov[2] = f2b(o[2] * inv); ov[3] = f2b(o[3] * inv);
    *(u16x4*)&Ob[(size_t)(b * S_ + i0 + i) * D_ + h * DH_ + dg * 4] = ov;
}

// ---------------------------------------------------------------------------
// Fused final softmax + broadcast: block = (token t, quarter of row-range).
// Each block re-computes softmax(t) (cheap, 4x redundant) then streams 128
// rows of 2KB with nontemporal float4 stores.
// ---------------------------------------------------------------------------
__global__ __launch_bounds__(256) void bcast_k(const float* __restrict__ Lg,
    const float* __restrict__ temp, float* __restrict__ out)
{
    __shared__ float row[V_];
    __shared__ float red[4];
    const int blk = blockIdx.x, t = blk >> 2, quarter = blk & 3;
    const int tid = threadIdx.x;
    const float rT = 1.f / temp[0];
    const float l0 = Lg[(size_t)t * V_ + tid] * rT;
    const float l1 = Lg[(size_t)t * V_ + 256 + tid] * rT;
    float m = waveReduceMax(fmaxf(l0, l1));
    if ((tid & 63) == 0) red[tid >> 6] = m;
    __syncthreads();
    m = fmaxf(fmaxf(red[0], red[1]), fmaxf(red[2], red[3]));
    __syncthreads();
    const float e0 = __expf(l0 - m), e1 = __expf(l1 - m);
    float sblk = waveReduceSum(e0 + e1);
    if ((tid & 63) == 0) red[tid >> 6] = sblk;
    __syncthreads();
    const float inv = 1.f / (red[0] + red[1] + red[2] + red[3]);
    row[tid] = e0 * inv;
    row[tid + 256] = e1 * inv;
    __syncthreads();

    const int c = tid & 127, ihalf = tid >> 7;
    f32x4 v = *(const f32x4*)&row[c * 4];
    f32x4* dst = (f32x4*)out + (size_t)t * V_ * (V_ / 4);
#pragma unroll 4
    for (int r = 0; r < 64; ++r) {
        const int i = quarter * 128 + ihalf + r * 2;
        __builtin_nontemporal_store(v, &dst[(size_t)i * (V_ / 4) + c]);
    }
}

// ---------------------------------------------------------------------------
// Host launch. ws layout (bytes), total 10.0 MB:
//   0        X     fp32 512KB
//   524288   PartA fp32 2x512KB (split-K parts 0-1; alias Lg 1MB at end)
//   1572864  Qb    bf16 256KB  \
//   1835008  Kb    bf16 256KB   } parts 2-3 alias this 1MB during W2 GEMM
//   2097152  Vb    bf16 256KB   } (Qb..Ob dead at that point in the layer)
//   2359296  Ob    bf16 256KB  /
//   2621440  Xb    bf16 256KB
//   2883584  Ffb   bf16 2MB
//   4980736  embB  bf16 256KB
//   5242880  WT    bf16 1MB
//   6291456  W1T   bf16 2MB
//   8388608  W2T   bf16 2MB   -> end 10485760
// ---------------------------------------------------------------------------
extern "C" void kernel_launch(void* const* d_in, const int* in_sizes, int n_in,
                              void* d_out, int out_size, void* d_ws, size_t ws_size,
                              hipStream_t stream)
{
    const int*   x_t  = (const int*)  d_in[0];
    const float* emb  = (const float*)d_in[1];
    const float* temp = (const float*)d_in[2];
    const float* Wq   = (const float*)d_in[3];
    const float* Wk   = (const float*)d_in[4];
    const float* Wv   = (const float*)d_in[5];
    const float* Wo   = (const float*)d_in[6];
    const float* bq   = (const float*)d_in[7];
    const float* bk   = (const float*)d_in[8];
    const float* bv   = (const float*)d_in[9];
    const float* bo   = (const float*)d_in[10];
    const float* W1   = (const float*)d_in[11];
    const float* b1   = (const float*)d_in[12];
    const float* W2   = (const float*)d_in[13];
    const float* b2   = (const float*)d_in[14];
    const float* ln1s = (const float*)d_in[15];
    const float* ln1b = (const float*)d_in[16];
    const float* ln2s = (const float*)d_in[17];
    const float* ln2b = (const float*)d_in[18];

    float* out = (float*)d_out;
    char*  wsb = (char*)d_ws;

    float*    X     = (float*)   (wsb + 0);
    float*    PartA = (float*)   (wsb + 524288);
    float*    Lg    = PartA;                        // alias (disjoint lifetime)
    ushort_t* Qb    = (ushort_t*)(wsb + 1572864);
    float*    PartB = (float*)   (wsb + 1572864);   // alias Qb..Ob (parts 2-3)
    ushort_t* Kb    = (ushort_t*)(wsb + 1835008);
    ushort_t* Vb    = (ushort_t*)(wsb + 2097152);
    ushort_t* Ob    = (ushort_t*)(wsb + 2359296);
    ushort_t* Xb    = (ushort_t*)(wsb + 2621440);
    ushort_t* Ffb   = (ushort_t*)(wsb + 2883584);
    ushort_t* embB  = (ushort_t*)(wsb + 4980736);
    ushort_t* WT    = (ushort_t*)(wsb + 5242880);
    ushort_t* W1T   = (ushort_t*)(wsb + 6291456);
    ushort_t* W2T   = (ushort_t*)(wsb + 8388608);

    prep_k<<<3072, 256, 0, stream>>>(x_t, emb, X, Xb, embB,
                                     Wq, Wk, Wv, Wo, W1, W2, WT, W1T, W2T);

    for (int l = 0; l < L_; ++l) {
        const ushort_t* WTl  = WT  + (size_t)l * (4 * D_ * D_);
        const ushort_t* W1Tl = W1T + (size_t)l * (D_ * FF_);
        const ushort_t* W2Tl = W2T + (size_t)l * (FF_ * D_);

        qkv_k<<<dim3(4, 8, 3), 256, 0, stream>>>(
            Xb, WTl, bq + l * D_, bk + l * D_, bv + l * D_, Qb, Kb, Vb);

        attn_k<<<dim3(32, 4), 256, 0, stream>>>(Qb, Kb, Vb, Ob);

        // o @ Wo split-K z=2 -> PartA[0..1]; bias bo folded into add_ln
        mgemm_k<0, 0, 0><<<dim3(4, 8, 2), 256, 0, stream>>>(
            Ob, WTl + 3 * D_ * D_, nullptr, PartA, nullptr, nullptr,
            T_, D_, D_, D_ / 2);
        add_ln_k<<<T_, 256, 0, stream>>>(PartA, nullptr, 2, bo + l * D_,
                                         X, Xb, ln1s + l * D_, ln1b + l * D_);

        // relu(x @ W1 + b1) -> Ffb (bf16)
        mgemm_k<1, 1, 1><<<dim3(32, 8, 1), 256, 0, stream>>>(
            Xb, W1Tl, b1 + l * FF_, nullptr, nullptr, Ffb, T_, FF_, D_, D_);

        // Ffb @ W2 split-K z=4 -> PartA[0..1] + PartB[0..1]; b2 in add_ln
        mgemm_k<0, 0, 0><<<dim3(4, 8, 4), 256, 0, stream>>>(
            Ffb, W2Tl, nullptr, PartA, PartB, nullptr, T_, D_, FF_, FF_ / 4);
        add_ln_k<<<T_, 256, 0, stream>>>(PartA, PartB, 4, b2 + l * D_,
                                         X, Xb, ln2s + l * D_, ln2b + l * D_);
    }

    // logits = Xb @ embB^T -> Lg (fp32)
    mgemm_k<0, 0, 0><<<dim3(8, 8, 1), 256, 0, stream>>>(
        Xb, embB, nullptr, Lg, nullptr, nullptr, T_, V_, D_, D_);

    bcast_k<<<T_ * 4, 256, 0, stream>>>(Lg, temp, out);
}